// Round 5
// baseline (261.631 us; speedup 1.0000x reference)
//
#include <hip/hip_runtime.h>

// DownSample fused: gather(knn) -> LayerNorm(C=128) -> Linear(128->256, MFMA) -> maxpool(k=16)
// Outputs concatenated: out[m,256] f32 | n_p[m,3] f32 | n_o[4] as f32
//
// R9: VALU/addressing hoist. R8 showed ~318 VALU instr/wave/iter (VALUBusy 35%)
// vs ~80 of real math -- address recomputation dominates the dominant pipe.
// Changes (data layout / arithmetic / schedule IDENTICAL to R8, which passed):
//  - ds_read swizzle separates: addr = lane_const(s) + ql*2048 + buf*8192.
//    4 precomputed bases; 16 reads use compile-time offset immediates.
//  - DMA src = SGPR base + 32b voffset (v_lshl_add_u32), computed 1 iter early.
//  - Stores: lane-const voffset + uniform base advanced by SALU + imm jp*512.
//  - template<bool EXACT>: mq%BQ==0 drops min() clamps and q<mq guards.
//  - __launch_bounds__(512,8) pins <=64 VGPR (R8 sat at 64 naturally).
// Fallback (ws too small): R4 single-pass bf16 kernel, verbatim.

#define C_IN   128
#define C_OUT  256
#define KNN    16
#define LN_EPS 1e-5f
#define BQ     4
#define ROWS   (BQ * KNN)       // 64
#define WAVES  8
#define BLOCK  (WAVES * 64)     // 512
#define NBLK   1024
#define BROW   128              // bytes per fp8 row
#define BUFB   (ROWS * BROW)    // 8 KB per buffer
#define BSCL   16.0f
#define IBSCL  (1.0f / 16.0f)

typedef __attribute__((ext_vector_type(8))) short  short8;
typedef __attribute__((ext_vector_type(4))) short  short4_t;
typedef __attribute__((ext_vector_type(8))) __bf16 bf16x8;
typedef __attribute__((ext_vector_type(4))) float  f32x4;

__device__ __forceinline__ short f2bf_bits(float f) {
    unsigned u = __float_as_uint(f);
    u += 0x7fffu + ((u >> 16) & 1u);   // round-to-nearest-even
    return (short)(u >> 16);
}

// ---- fp8 e4m3 (OCP) packing: 2 floats -> 2 bytes in low/high half of a u32 ----
#if defined(__has_builtin) && __has_builtin(__builtin_amdgcn_cvt_pk_fp8_f32)
__device__ __forceinline__ unsigned pk2fp8(float a, float b, unsigned old, bool hi) {
    return hi ? (unsigned)__builtin_amdgcn_cvt_pk_fp8_f32(a, b, (int)old, true)
              : (unsigned)__builtin_amdgcn_cvt_pk_fp8_f32(a, b, (int)old, false);
}
#else
__device__ __forceinline__ unsigned fp8e4m3_byte(float f) {
    unsigned u = __float_as_uint(f);
    const unsigned sgn = (u >> 24) & 0x80u;
    const float af = __uint_as_float(u & 0x7fffffffu);
    if (!(af < 448.f)) return sgn | 0x7Eu;          // saturate
    if (af < 0.015625f) {                           // subnormal: q * 2^-9
        int q = (int)(af * 512.f + 0.5f);
        return (q > 7) ? (sgn | 0x08u) : (sgn | (unsigned)q);
    }
    unsigned au = u & 0x7fffffffu;
    au += 0x7FFFFu + ((au >> 20) & 1u);             // RNE to 3 mantissa bits
    const int e = (int)(au >> 23) - 127;
    if (e > 8) return sgn | 0x7Eu;
    return sgn | ((unsigned)(e + 7) << 3) | ((au >> 20) & 7u);
}
__device__ __forceinline__ unsigned pk2fp8(float a, float b, unsigned old, bool hi) {
    const unsigned p = fp8e4m3_byte(a) | (fp8e4m3_byte(b) << 8);
    return hi ? ((old & 0xffffu) | (p << 16)) : ((old & 0xffff0000u) | p);
}
#endif

__device__ __forceinline__ void gl_lds16b(const void* src, void* dst) {
    __builtin_amdgcn_global_load_lds(
        (const __attribute__((address_space(1))) void*)src,
        (__attribute__((address_space(3))) void*)dst, 16, 0, 0);
}

// ---------------------------------------------------------------------------
// Pass A: LayerNorm(x[n,128]) -> fp8 e4m3 rows in workspace. 32 threads/row.
// ---------------------------------------------------------------------------
__global__ __launch_bounds__(256) void lnq_kernel(
    const float* __restrict__ x, unsigned* __restrict__ xq, int n)
{
    const int r = blockIdx.x * 8 + (threadIdx.x >> 5);
    const int c = threadIdx.x & 31;
    if (r >= n) return;
    const float4 v = *(const float4*)(x + (long long)r * C_IN + c * 4);
    float s1 = v.x + v.y + v.z + v.w;
    float s2 = v.x * v.x + v.y * v.y + v.z * v.z + v.w * v.w;
    #pragma unroll
    for (int off = 1; off < 32; off <<= 1) {
        s1 += __shfl_xor(s1, off);
        s2 += __shfl_xor(s2, off);
    }
    const float mu   = s1 * (1.f / 128.f);
    const float rstd = rsqrtf(s2 * (1.f / 128.f) - mu * mu + LN_EPS);
    unsigned p = pk2fp8((v.x - mu) * rstd, (v.y - mu) * rstd, 0u, false);
    p = pk2fp8((v.z - mu) * rstd, (v.w - mu) * rstd, p, true);
    xq[(long long)r * 32 + c] = p;
}

// ---------------------------------------------------------------------------
// Pass B: gather fp8 rows -> LDS (1 DMA/wave/iter, source-side swizzle)
//         -> fp8 MFMA -> maxpool -> store. One barrier per 4 queries.
// ---------------------------------------------------------------------------
template<bool EXACT>
__global__ __launch_bounds__(BLOCK, 8) void fused_gather_kernel(
    const unsigned char* __restrict__ xq, const int* __restrict__ knn,
    const float* __restrict__ nw, const float* __restrict__ nb,
    const float* __restrict__ W,
    const float* __restrict__ n_p, const int* __restrict__ n_o,
    float* __restrict__ out, float* __restrict__ out_np, float* __restrict__ out_no,
    int mq, int npcnt)
{
    // 2 buffers x 64 rows x 128B. LDS 16B-block p of row r holds source block
    // p ^ (r&7) (source-side swizzle; linear DMA dest). Same layout as R8.
    __shared__ __align__(16) char Ash[2 * BUFB];   // 16 KB
    char* const AshC = Ash;

    const int tid  = threadIdx.x;
    const int lane = tid & 63;
    const int wave = tid >> 6;          // wave w owns out cols [w*32, w*32+32)
    const int m16  = lane & 15;
    const int qd   = lane >> 4;
    const int q1   = qd & 1;
    const int h2   = qd >> 1;
    const int m7   = m16 & 7;

    const int g    = gridDim.x;
    const int nbat = (mq + BQ - 1) / BQ;
    const int nk   = mq * KNN;

    // Gather roles: wave w stages rows [w*8, w*8+8) via ONE global_load_lds.
    const int myrow = wave * 8 + (lane >> 3);
    const unsigned sboff = (unsigned)((((lane & 7) ^ (myrow & 7)) * 16));
    char* const dwave = AshC + wave * 1024;          // DMA dest base (buf0)

    // Lane-constant ds_read bases: full addr = aoff[s] + ql*2048 + bufoff.
    int aoff[4];
    #pragma unroll
    for (int s = 0; s < 4; ++s)
        aoff[s] = m16 * BROW + (((s * 2 + h2) ^ m7) * 16) + q1 * 8;

    // Lane-constant store float-offset within a 4-query group.
    const int vo = wave * 32 + q1 * 16 + m16 + h2 * C_OUT;

    int bat = blockIdx.x;
    int i0;
    if (EXACT) i0 = knn[bat * ROWS + myrow];
    else       i0 = knn[min(bat * ROWS + myrow, nk - 1)];

    // ---- preamble: B frags = fp8(W[n][k]*nw[k]*16); c[n] = sum_k nb[k]W[n][k]
    long  bfr[2][4];                    // [col-tile][k-step]
    float cp0 = 0.f, cp1 = 0.f;
    #pragma unroll
    for (int s = 0; s < 4; ++s) {
        const int k0 = s * 32 + qd * 8;
        const float4 a0 = *(const float4*)(nw + k0);
        const float4 a1 = *(const float4*)(nw + k0 + 4);
        const float4 c0 = *(const float4*)(nb + k0);
        const float4 c1 = *(const float4*)(nb + k0 + 4);
        const float nwv[8] = {a0.x,a0.y,a0.z,a0.w,a1.x,a1.y,a1.z,a1.w};
        const float nbv[8] = {c0.x,c0.y,c0.z,c0.w,c1.x,c1.y,c1.z,c1.w};
        #pragma unroll
        for (int t = 0; t < 2; ++t) {
            const int n_ = wave * 32 + t * 16 + m16;
            const float4* wp = (const float4*)(W + n_ * C_IN + k0);
            const float4 w0 = wp[0], w1 = wp[1];
            const float wvv[8] = {w0.x,w0.y,w0.z,w0.w,w1.x,w1.y,w1.z,w1.w};
            float cacc = 0.f;
            #pragma unroll
            for (int j = 0; j < 8; ++j) cacc += nbv[j] * wvv[j];
            unsigned lo = pk2fp8(wvv[0]*nwv[0]*BSCL, wvv[1]*nwv[1]*BSCL, 0u, false);
            lo = pk2fp8(wvv[2]*nwv[2]*BSCL, wvv[3]*nwv[3]*BSCL, lo, true);
            unsigned hi = pk2fp8(wvv[4]*nwv[4]*BSCL, wvv[5]*nwv[5]*BSCL, 0u, false);
            hi = pk2fp8(wvv[6]*nwv[6]*BSCL, wvv[7]*nwv[7]*BSCL, hi, true);
            bfr[t][s] = (long)(((unsigned long long)hi << 32) | lo);
            if (t == 0) cp0 += cacc; else cp1 += cacc;
        }
    }
    cp0 += __shfl_xor(cp0, 16); cp0 += __shfl_xor(cp0, 32);
    cp1 += __shfl_xor(cp1, 16); cp1 += __shfl_xor(cp1, 32);

    // ---- prime: gather batch `bat` into buf0; prefetch idx+addr for batch +g
    gl_lds16b(xq + (((unsigned)i0 << 7) + sboff), dwave);
    {
        const int b1 = (bat + g < nbat) ? (bat + g) : bat;
        int inext;
        if (EXACT) inext = knn[b1 * ROWS + myrow];
        else       inext = knn[min(b1 * ROWS + myrow, nk - 1)];
        i0 = inext;                     // reuse i0 as "next index"
    }
    unsigned srcnext = ((unsigned)i0 << 7) + sboff;

    float* ob = out + (long long)bat * (BQ * C_OUT);
    const long long ostep = (long long)g * (BQ * C_OUT);
    int bufoff = 0;

    for (; bat < nbat; bat += g) {
        // compiler emits s_waitcnt vmcnt(0) lgkmcnt(0) before s_barrier ->
        // buf's DMA writes complete; prior iter's LDS reads drained.
        __syncthreads();

        // ---- issue next batch's gather NOW (in flight during MFMA below) ----
        if (bat + g < nbat) {
            gl_lds16b(xq + srcnext, dwave + (bufoff ^ BUFB));
            const int b2 = (bat + 2 * g < nbat) ? (bat + 2 * g) : (bat + g);
            int inext;
            if (EXACT) inext = knn[b2 * ROWS + myrow];
            else       inext = knn[min(b2 * ROWS + myrow, nk - 1)];
            srcnext = ((unsigned)inext << 7) + sboff;   // ready for next iter
        }

        const char* Ab = AshC + bufoff;

        // ---- MFMA + maxpool for the 4 queries; paired 64-lane stores ----
        #pragma unroll
        for (int jp = 0; jp < 2; ++jp) {
            float ra0, ra1, rb0, rb1;
            #pragma unroll
            for (int half = 0; half < 2; ++half) {
                const int ql = jp * 2 + half;
                long afr[4];
                #pragma unroll
                for (int s = 0; s < 4; ++s)
                    afr[s] = *(const long*)(Ab + aoff[s] + ql * 2048);
                f32x4 acc0 = {0,0,0,0}, acc1 = {0,0,0,0};
                #pragma unroll
                for (int s = 0; s < 4; ++s) {
                    acc0 = __builtin_amdgcn_mfma_f32_16x16x32_fp8_fp8(
                        afr[s], bfr[0][s], acc0, 0, 0, 0);
                    acc1 = __builtin_amdgcn_mfma_f32_16x16x32_fp8_fp8(
                        afr[s], bfr[1][s], acc1, 0, 0, 0);
                }
                float v0 = fmaxf(fmaxf(fmaxf(acc0[0], acc0[1]), acc0[2]), acc0[3]);
                v0 = fmaxf(v0, __shfl_xor(v0, 16));
                v0 = fmaxf(v0, __shfl_xor(v0, 32));
                float v1 = fmaxf(fmaxf(fmaxf(acc1[0], acc1[1]), acc1[2]), acc1[3]);
                v1 = fmaxf(v1, __shfl_xor(v1, 16));
                v1 = fmaxf(v1, __shfl_xor(v1, 32));
                if (half == 0) { ra0 = v0; ra1 = v1; }
                else           { rb0 = v0; rb1 = v1; }
            }
            // lanes h2=0: query jp*2, lanes h2=1: query jp*2+1
            const float s0 = h2 ? rb0 : ra0;
            const float s1 = h2 ? rb1 : ra1;
            const float val = (q1 ? s1 : s0) * IBSCL + (q1 ? cp1 : cp0);
            if (EXACT) {
                ob[vo + jp * 512] = val;
            } else {
                const int q = bat * BQ + jp * 2 + h2;
                if (q < mq) ob[vo + jp * 512] = val;
            }
        }
        bufoff ^= BUFB;
        ob += ostep;
    }

    // ---- passthrough outputs ----
    const int gtid = blockIdx.x * BLOCK + tid;
    const int gstr = g * BLOCK;
    const int np4 = npcnt >> 2;
    for (int i = gtid; i < np4; i += gstr)
        ((float4*)out_np)[i] = ((const float4*)n_p)[i];
    for (int i = (np4 << 2) + gtid; i < npcnt; i += gstr) out_np[i] = n_p[i];
    if (gtid < 4) out_no[gtid] = (float)n_o[gtid];
}

// ---------------------------------------------------------------------------
// Fallback: single-pass bf16 kernel (R4, proven) for when ws_size is too small.
// ---------------------------------------------------------------------------
__global__ __launch_bounds__(256) void fused_inline_kernel(
    const float* __restrict__ x, const int* __restrict__ knn,
    const float* __restrict__ nw, const float* __restrict__ nb,
    const float* __restrict__ W,
    const float* __restrict__ n_p, const int* __restrict__ n_o,
    float* __restrict__ out, float* __restrict__ out_np, float* __restrict__ out_no,
    int mq, int npcnt)
{
    __shared__ __align__(16) short Ash[2 * 32 * C_IN];

    const int tid  = threadIdx.x;
    const int lane = tid & 63;
    const int wave = tid >> 6;
    const int m16  = lane & 15;
    const int qd   = lane >> 4;

    short8 bfrag[4][4];
    float  cpart[4] = {0.f, 0.f, 0.f, 0.f};
    #pragma unroll
    for (int s = 0; s < 4; ++s) {
        const int k0 = s * 32 + qd * 8;
        const float4 a0 = *(const float4*)(nw + k0);
        const float4 a1 = *(const float4*)(nw + k0 + 4);
        const float4 c0 = *(const float4*)(nb + k0);
        const float4 c1 = *(const float4*)(nb + k0 + 4);
        const float nwv[8] = {a0.x,a0.y,a0.z,a0.w,a1.x,a1.y,a1.z,a1.w};
        const float nbv[8] = {c0.x,c0.y,c0.z,c0.w,c1.x,c1.y,c1.z,c1.w};
        #pragma unroll
        for (int t = 0; t < 4; ++t) {
            const int n = wave * 64 + t * 16 + m16;
            const float4* wp = (const float4*)(W + n * C_IN + k0);
            const float4 w0 = wp[0], w1 = wp[1];
            const float wvv[8] = {w0.x,w0.y,w0.z,w0.w,w1.x,w1.y,w1.z,w1.w};
            short8 b;
            #pragma unroll
            for (int j = 0; j < 8; ++j) {
                b[j] = f2bf_bits(wvv[j] * nwv[j]);
                cpart[t] += nbv[j] * wvv[j];
            }
            bfrag[t][s] = b;
        }
    }
    #pragma unroll
    for (int t = 0; t < 4; ++t) {
        cpart[t] += __shfl_xor(cpart[t], 16);
        cpart[t] += __shfl_xor(cpart[t], 32);
    }
    const float cbias = (qd == 0) ? cpart[0] : (qd == 1) ? cpart[1]
                      : (qd == 2) ? cpart[2] : cpart[3];

    const int sr = tid >> 3;
    const int sc = tid & 7;

    const int nbat = (mq + 1) / 2;
    const int g = gridDim.x;
    const int nk = mq * KNN;

    int bat = blockIdx.x;
    float4 pf[4];
    int idxn;
    {
        const int id0 = knn[min(bat * 32 + sr, nk - 1)];
        const float* xr = x + (long long)id0 * C_IN + sc * 4;
        #pragma unroll
        for (int t = 0; t < 4; ++t) pf[t] = *(const float4*)(xr + t * 32);
        const int b1 = (bat + g < nbat) ? (bat + g) : bat;
        idxn = knn[min(b1 * 32 + sr, nk - 1)];
    }

    int buf = 0;
    for (; bat < nbat; bat += g) {
        float s1 = 0.f, s2 = 0.f;
        #pragma unroll
        for (int t = 0; t < 4; ++t) {
            s1 += pf[t].x + pf[t].y + pf[t].z + pf[t].w;
            s2 += pf[t].x*pf[t].x + pf[t].y*pf[t].y + pf[t].z*pf[t].z + pf[t].w*pf[t].w;
        }
        #pragma unroll
        for (int off = 1; off < 8; off <<= 1) {
            s1 += __shfl_xor(s1, off);
            s2 += __shfl_xor(s2, off);
        }
        const float mu   = s1 * (1.f / 128.f);
        const float rstd = rsqrtf(s2 * (1.f / 128.f) - mu * mu + LN_EPS);
        #pragma unroll
        for (int t = 0; t < 4; ++t) {
            short4_t hb;
            hb[0] = f2bf_bits((pf[t].x - mu) * rstd);
            hb[1] = f2bf_bits((pf[t].y - mu) * rstd);
            hb[2] = f2bf_bits((pf[t].z - mu) * rstd);
            hb[3] = f2bf_bits((pf[t].w - mu) * rstd);
            const int pb = ((sc >> 1) + 4 * t) ^ (sr & 15);
            *(short4_t*)&Ash[buf * 4096 + sr * 128 + pb * 8 + (sc & 1) * 4] = hb;
        }
        __syncthreads();

        if (bat + g < nbat) {
            const float* xr = x + (long long)idxn * C_IN + sc * 4;
            #pragma unroll
            for (int t = 0; t < 4; ++t) pf[t] = *(const float4*)(xr + t * 32);
            const int b2 = (bat + 2 * g < nbat) ? (bat + 2 * g) : (bat + g);
            idxn = knn[min(b2 * 32 + sr, nk - 1)];
        }

        #pragma unroll
        for (int ql = 0; ql < 2; ++ql) {
            short8 afrag[4];
            #pragma unroll
            for (int s = 0; s < 4; ++s) {
                const int pb = (s * 4 + qd) ^ m16;
                afrag[s] = *(const short8*)&Ash[buf * 4096 + (ql * 16 + m16) * 128 + pb * 8];
            }
            f32x4 acc[4] = {{0,0,0,0},{0,0,0,0},{0,0,0,0},{0,0,0,0}};
            #pragma unroll
            for (int s = 0; s < 4; ++s) {
                const bf16x8 av = __builtin_bit_cast(bf16x8, afrag[s]);
                #pragma unroll
                for (int t = 0; t < 4; ++t)
                    acc[t] = __builtin_amdgcn_mfma_f32_16x16x32_bf16(
                        av, __builtin_bit_cast(bf16x8, bfrag[t][s]), acc[t], 0, 0, 0);
            }
            float r[4];
            #pragma unroll
            for (int t = 0; t < 4; ++t) {
                float v = fmaxf(fmaxf(acc[t][0], acc[t][1]), fmaxf(acc[t][2], acc[t][3]));
                v = fmaxf(v, __shfl_xor(v, 16));
                v = fmaxf(v, __shfl_xor(v, 32));
                r[t] = v;
            }
            const float vout = ((qd == 0) ? r[0] : (qd == 1) ? r[1]
                              : (qd == 2) ? r[2] : r[3]) + cbias;
            const int q = bat * 2 + ql;
            if (q < mq) out[q * C_OUT + wave * 64 + lane] = vout;
        }
        buf ^= 1;
    }

    const int gtid = blockIdx.x * 256 + tid;
    const int gstr = g * 256;
    const int np4 = npcnt >> 2;
    for (int i = gtid; i < np4; i += gstr)
        ((float4*)out_np)[i] = ((const float4*)n_p)[i];
    for (int i = (np4 << 2) + gtid; i < npcnt; i += gstr) out_np[i] = n_p[i];
    if (gtid < 4) out_no[gtid] = (float)n_o[gtid];
}

extern "C" void kernel_launch(void* const* d_in, const int* in_sizes, int n_in,
                              void* d_out, int out_size, void* d_ws, size_t ws_size,
                              hipStream_t stream)
{
    const float* x   = (const float*)d_in[1];
    const float* n_p = (const float*)d_in[3];
    const int*   knn = (const int*)  d_in[4];
    const int*   n_o = (const int*)  d_in[5];
    const float* nw  = (const float*)d_in[6];
    const float* nb  = (const float*)d_in[7];
    const float* W   = (const float*)d_in[8];
    float* out = (float*)d_out;

    // in_sizes are ELEMENT counts (mq = in_sizes[4]/16 = 50000 proves it).
    const int n     = in_sizes[1] / C_IN;   // 200000 source rows
    const int mq    = in_sizes[4] / KNN;    // 50000
    const int npcnt = in_sizes[3];          // 150000
    float* out_np = out + (size_t)mq * C_OUT;
    float* out_no = out_np + npcnt;

    const size_t ws_need = (size_t)n * BROW;   // 25.6 MB fp8 table
    if (ws_size >= ws_need) {
        unsigned* xq = (unsigned*)d_ws;
        const int nbat = (mq + BQ - 1) / BQ;
        const int grid = (nbat < NBLK) ? nbat : NBLK;
        hipLaunchKernelGGL(lnq_kernel, dim3((n + 7) / 8), dim3(256), 0, stream,
                           x, xq, n);
        if (mq % BQ == 0) {
            hipLaunchKernelGGL(fused_gather_kernel<true>, dim3(grid), dim3(BLOCK), 0,
                               stream, (const unsigned char*)xq, knn, nw, nb, W,
                               n_p, n_o, out, out_np, out_no, mq, npcnt);
        } else {
            hipLaunchKernelGGL(fused_gather_kernel<false>, dim3(grid), dim3(BLOCK), 0,
                               stream, (const unsigned char*)xq, knn, nw, nb, W,
                               n_p, n_o, out, out_np, out_no, mq, npcnt);
        }
    } else {
        hipLaunchKernelGGL(fused_inline_kernel, dim3(NBLK), dim3(256), 0, stream,
                           x, knn, nw, nb, W, n_p, n_o, out, out_np, out_no, mq, npcnt);
    }
}

// Round 6
// 246.517 us; speedup vs baseline: 1.0613x; 1.0613x over previous
//
#include <hip/hip_runtime.h>

// DownSample fused: gather(knn) -> LayerNorm(C=128) -> Linear(128->256, MFMA) -> maxpool(k=16)
// Outputs concatenated: out[m,256] f32 | n_p[m,3] f32 | n_o[4] as f32
//
// R10 = R9 with the launch-bounds poison removed. R9's __launch_bounds__(512,8)
// pinned 32 VGPR -> scratch spills (WRITE 50.6->134.5MB, FETCH 48->88.8MB,
// 74.5->93.5us) -- exact repeat of the R3 failure mode recorded in the header.
// This round: __launch_bounds__(BLOCK) only; everything else identical to R9:
//  - ds_read swizzle hoisted: addr = lane_const(s) + ql*2048 + bufoff (imm).
//  - DMA src = SGPR base + 32b voffset, computed 1 iter early.
//  - Stores: lane-const voffset + uniform base advanced per iter + imm jp*512.
//  - template<bool EXACT>: mq%BQ==0 drops clamps/guards (mq=50000, BQ=4).
// Fallback (ws too small): R4 single-pass bf16 kernel, verbatim.

#define C_IN   128
#define C_OUT  256
#define KNN    16
#define LN_EPS 1e-5f
#define BQ     4
#define ROWS   (BQ * KNN)       // 64
#define WAVES  8
#define BLOCK  (WAVES * 64)     // 512
#define NBLK   1024
#define BROW   128              // bytes per fp8 row
#define BUFB   (ROWS * BROW)    // 8 KB per buffer
#define BSCL   16.0f
#define IBSCL  (1.0f / 16.0f)

typedef __attribute__((ext_vector_type(8))) short  short8;
typedef __attribute__((ext_vector_type(4))) short  short4_t;
typedef __attribute__((ext_vector_type(8))) __bf16 bf16x8;
typedef __attribute__((ext_vector_type(4))) float  f32x4;

__device__ __forceinline__ short f2bf_bits(float f) {
    unsigned u = __float_as_uint(f);
    u += 0x7fffu + ((u >> 16) & 1u);   // round-to-nearest-even
    return (short)(u >> 16);
}

// ---- fp8 e4m3 (OCP) packing: 2 floats -> 2 bytes in low/high half of a u32 ----
#if defined(__has_builtin) && __has_builtin(__builtin_amdgcn_cvt_pk_fp8_f32)
__device__ __forceinline__ unsigned pk2fp8(float a, float b, unsigned old, bool hi) {
    return hi ? (unsigned)__builtin_amdgcn_cvt_pk_fp8_f32(a, b, (int)old, true)
              : (unsigned)__builtin_amdgcn_cvt_pk_fp8_f32(a, b, (int)old, false);
}
#else
__device__ __forceinline__ unsigned fp8e4m3_byte(float f) {
    unsigned u = __float_as_uint(f);
    const unsigned sgn = (u >> 24) & 0x80u;
    const float af = __uint_as_float(u & 0x7fffffffu);
    if (!(af < 448.f)) return sgn | 0x7Eu;          // saturate
    if (af < 0.015625f) {                           // subnormal: q * 2^-9
        int q = (int)(af * 512.f + 0.5f);
        return (q > 7) ? (sgn | 0x08u) : (sgn | (unsigned)q);
    }
    unsigned au = u & 0x7fffffffu;
    au += 0x7FFFFu + ((au >> 20) & 1u);             // RNE to 3 mantissa bits
    const int e = (int)(au >> 23) - 127;
    if (e > 8) return sgn | 0x7Eu;
    return sgn | ((unsigned)(e + 7) << 3) | ((au >> 20) & 7u);
}
__device__ __forceinline__ unsigned pk2fp8(float a, float b, unsigned old, bool hi) {
    const unsigned p = fp8e4m3_byte(a) | (fp8e4m3_byte(b) << 8);
    return hi ? ((old & 0xffffu) | (p << 16)) : ((old & 0xffff0000u) | p);
}
#endif

__device__ __forceinline__ void gl_lds16b(const void* src, void* dst) {
    __builtin_amdgcn_global_load_lds(
        (const __attribute__((address_space(1))) void*)src,
        (__attribute__((address_space(3))) void*)dst, 16, 0, 0);
}

// ---------------------------------------------------------------------------
// Pass A: LayerNorm(x[n,128]) -> fp8 e4m3 rows in workspace. 32 threads/row.
// ---------------------------------------------------------------------------
__global__ __launch_bounds__(256) void lnq_kernel(
    const float* __restrict__ x, unsigned* __restrict__ xq, int n)
{
    const int r = blockIdx.x * 8 + (threadIdx.x >> 5);
    const int c = threadIdx.x & 31;
    if (r >= n) return;
    const float4 v = *(const float4*)(x + (long long)r * C_IN + c * 4);
    float s1 = v.x + v.y + v.z + v.w;
    float s2 = v.x * v.x + v.y * v.y + v.z * v.z + v.w * v.w;
    #pragma unroll
    for (int off = 1; off < 32; off <<= 1) {
        s1 += __shfl_xor(s1, off);
        s2 += __shfl_xor(s2, off);
    }
    const float mu   = s1 * (1.f / 128.f);
    const float rstd = rsqrtf(s2 * (1.f / 128.f) - mu * mu + LN_EPS);
    unsigned p = pk2fp8((v.x - mu) * rstd, (v.y - mu) * rstd, 0u, false);
    p = pk2fp8((v.z - mu) * rstd, (v.w - mu) * rstd, p, true);
    xq[(long long)r * 32 + c] = p;
}

// ---------------------------------------------------------------------------
// Pass B: gather fp8 rows -> LDS (1 DMA/wave/iter, source-side swizzle)
//         -> fp8 MFMA -> maxpool -> store. One barrier per 4 queries.
// ---------------------------------------------------------------------------
template<bool EXACT>
__global__ __launch_bounds__(BLOCK) void fused_gather_kernel(
    const unsigned char* __restrict__ xq, const int* __restrict__ knn,
    const float* __restrict__ nw, const float* __restrict__ nb,
    const float* __restrict__ W,
    const float* __restrict__ n_p, const int* __restrict__ n_o,
    float* __restrict__ out, float* __restrict__ out_np, float* __restrict__ out_no,
    int mq, int npcnt)
{
    // 2 buffers x 64 rows x 128B. LDS 16B-block p of row r holds source block
    // p ^ (r&7) (source-side swizzle; linear DMA dest). Same layout as R8.
    __shared__ __align__(16) char Ash[2 * BUFB];   // 16 KB
    char* const AshC = Ash;

    const int tid  = threadIdx.x;
    const int lane = tid & 63;
    const int wave = tid >> 6;          // wave w owns out cols [w*32, w*32+32)
    const int m16  = lane & 15;
    const int qd   = lane >> 4;
    const int q1   = qd & 1;
    const int h2   = qd >> 1;
    const int m7   = m16 & 7;

    const int g    = gridDim.x;
    const int nbat = (mq + BQ - 1) / BQ;
    const int nk   = mq * KNN;

    // Gather roles: wave w stages rows [w*8, w*8+8) via ONE global_load_lds.
    const int myrow = wave * 8 + (lane >> 3);
    const unsigned sboff = (unsigned)((((lane & 7) ^ (myrow & 7)) * 16));
    char* const dwave = AshC + wave * 1024;          // DMA dest base (buf0)

    // Lane-constant ds_read bases: full addr = aoff[s] + ql*2048 + bufoff.
    int aoff[4];
    #pragma unroll
    for (int s = 0; s < 4; ++s)
        aoff[s] = m16 * BROW + (((s * 2 + h2) ^ m7) * 16) + q1 * 8;

    // Lane-constant store float-offset within a 4-query group.
    const int vo = wave * 32 + q1 * 16 + m16 + h2 * C_OUT;

    int bat = blockIdx.x;
    int i0;
    if (EXACT) i0 = knn[bat * ROWS + myrow];
    else       i0 = knn[min(bat * ROWS + myrow, nk - 1)];

    // ---- preamble: B frags = fp8(W[n][k]*nw[k]*16); c[n] = sum_k nb[k]W[n][k]
    long  bfr[2][4];                    // [col-tile][k-step]
    float cp0 = 0.f, cp1 = 0.f;
    #pragma unroll
    for (int s = 0; s < 4; ++s) {
        const int k0 = s * 32 + qd * 8;
        const float4 a0 = *(const float4*)(nw + k0);
        const float4 a1 = *(const float4*)(nw + k0 + 4);
        const float4 c0 = *(const float4*)(nb + k0);
        const float4 c1 = *(const float4*)(nb + k0 + 4);
        const float nwv[8] = {a0.x,a0.y,a0.z,a0.w,a1.x,a1.y,a1.z,a1.w};
        const float nbv[8] = {c0.x,c0.y,c0.z,c0.w,c1.x,c1.y,c1.z,c1.w};
        #pragma unroll
        for (int t = 0; t < 2; ++t) {
            const int n_ = wave * 32 + t * 16 + m16;
            const float4* wp = (const float4*)(W + n_ * C_IN + k0);
            const float4 w0 = wp[0], w1 = wp[1];
            const float wvv[8] = {w0.x,w0.y,w0.z,w0.w,w1.x,w1.y,w1.z,w1.w};
            float cacc = 0.f;
            #pragma unroll
            for (int j = 0; j < 8; ++j) cacc += nbv[j] * wvv[j];
            unsigned lo = pk2fp8(wvv[0]*nwv[0]*BSCL, wvv[1]*nwv[1]*BSCL, 0u, false);
            lo = pk2fp8(wvv[2]*nwv[2]*BSCL, wvv[3]*nwv[3]*BSCL, lo, true);
            unsigned hi = pk2fp8(wvv[4]*nwv[4]*BSCL, wvv[5]*nwv[5]*BSCL, 0u, false);
            hi = pk2fp8(wvv[6]*nwv[6]*BSCL, wvv[7]*nwv[7]*BSCL, hi, true);
            bfr[t][s] = (long)(((unsigned long long)hi << 32) | lo);
            if (t == 0) cp0 += cacc; else cp1 += cacc;
        }
    }
    cp0 += __shfl_xor(cp0, 16); cp0 += __shfl_xor(cp0, 32);
    cp1 += __shfl_xor(cp1, 16); cp1 += __shfl_xor(cp1, 32);

    // ---- prime: gather batch `bat` into buf0; prefetch idx+addr for batch +g
    gl_lds16b(xq + (((unsigned)i0 << 7) + sboff), dwave);
    {
        const int b1 = (bat + g < nbat) ? (bat + g) : bat;
        int inext;
        if (EXACT) inext = knn[b1 * ROWS + myrow];
        else       inext = knn[min(b1 * ROWS + myrow, nk - 1)];
        i0 = inext;                     // reuse i0 as "next index"
    }
    unsigned srcnext = ((unsigned)i0 << 7) + sboff;

    float* ob = out + (long long)bat * (BQ * C_OUT);
    const long long ostep = (long long)g * (BQ * C_OUT);
    int bufoff = 0;

    for (; bat < nbat; bat += g) {
        // compiler emits s_waitcnt vmcnt(0) lgkmcnt(0) before s_barrier ->
        // buf's DMA writes complete; prior iter's LDS reads drained.
        __syncthreads();

        // ---- issue next batch's gather NOW (in flight during MFMA below) ----
        if (bat + g < nbat) {
            gl_lds16b(xq + srcnext, dwave + (bufoff ^ BUFB));
            const int b2 = (bat + 2 * g < nbat) ? (bat + 2 * g) : (bat + g);
            int inext;
            if (EXACT) inext = knn[b2 * ROWS + myrow];
            else       inext = knn[min(b2 * ROWS + myrow, nk - 1)];
            srcnext = ((unsigned)inext << 7) + sboff;   // ready for next iter
        }

        const char* Ab = AshC + bufoff;

        // ---- MFMA + maxpool for the 4 queries; paired 64-lane stores ----
        #pragma unroll
        for (int jp = 0; jp < 2; ++jp) {
            float ra0, ra1, rb0, rb1;
            #pragma unroll
            for (int half = 0; half < 2; ++half) {
                const int ql = jp * 2 + half;
                long afr[4];
                #pragma unroll
                for (int s = 0; s < 4; ++s)
                    afr[s] = *(const long*)(Ab + aoff[s] + ql * 2048);
                f32x4 acc0 = {0,0,0,0}, acc1 = {0,0,0,0};
                #pragma unroll
                for (int s = 0; s < 4; ++s) {
                    acc0 = __builtin_amdgcn_mfma_f32_16x16x32_fp8_fp8(
                        afr[s], bfr[0][s], acc0, 0, 0, 0);
                    acc1 = __builtin_amdgcn_mfma_f32_16x16x32_fp8_fp8(
                        afr[s], bfr[1][s], acc1, 0, 0, 0);
                }
                float v0 = fmaxf(fmaxf(fmaxf(acc0[0], acc0[1]), acc0[2]), acc0[3]);
                v0 = fmaxf(v0, __shfl_xor(v0, 16));
                v0 = fmaxf(v0, __shfl_xor(v0, 32));
                float v1 = fmaxf(fmaxf(fmaxf(acc1[0], acc1[1]), acc1[2]), acc1[3]);
                v1 = fmaxf(v1, __shfl_xor(v1, 16));
                v1 = fmaxf(v1, __shfl_xor(v1, 32));
                if (half == 0) { ra0 = v0; ra1 = v1; }
                else           { rb0 = v0; rb1 = v1; }
            }
            // lanes h2=0: query jp*2, lanes h2=1: query jp*2+1
            const float s0 = h2 ? rb0 : ra0;
            const float s1 = h2 ? rb1 : ra1;
            const float val = (q1 ? s1 : s0) * IBSCL + (q1 ? cp1 : cp0);
            if (EXACT) {
                ob[vo + jp * 512] = val;
            } else {
                const int q = bat * BQ + jp * 2 + h2;
                if (q < mq) ob[vo + jp * 512] = val;
            }
        }
        bufoff ^= BUFB;
        ob += ostep;
    }

    // ---- passthrough outputs ----
    const int gtid = blockIdx.x * BLOCK + tid;
    const int gstr = g * BLOCK;
    const int np4 = npcnt >> 2;
    for (int i = gtid; i < np4; i += gstr)
        ((float4*)out_np)[i] = ((const float4*)n_p)[i];
    for (int i = (np4 << 2) + gtid; i < npcnt; i += gstr) out_np[i] = n_p[i];
    if (gtid < 4) out_no[gtid] = (float)n_o[gtid];
}

// ---------------------------------------------------------------------------
// Fallback: single-pass bf16 kernel (R4, proven) for when ws_size is too small.
// ---------------------------------------------------------------------------
__global__ __launch_bounds__(256) void fused_inline_kernel(
    const float* __restrict__ x, const int* __restrict__ knn,
    const float* __restrict__ nw, const float* __restrict__ nb,
    const float* __restrict__ W,
    const float* __restrict__ n_p, const int* __restrict__ n_o,
    float* __restrict__ out, float* __restrict__ out_np, float* __restrict__ out_no,
    int mq, int npcnt)
{
    __shared__ __align__(16) short Ash[2 * 32 * C_IN];

    const int tid  = threadIdx.x;
    const int lane = tid & 63;
    const int wave = tid >> 6;
    const int m16  = lane & 15;
    const int qd   = lane >> 4;

    short8 bfrag[4][4];
    float  cpart[4] = {0.f, 0.f, 0.f, 0.f};
    #pragma unroll
    for (int s = 0; s < 4; ++s) {
        const int k0 = s * 32 + qd * 8;
        const float4 a0 = *(const float4*)(nw + k0);
        const float4 a1 = *(const float4*)(nw + k0 + 4);
        const float4 c0 = *(const float4*)(nb + k0);
        const float4 c1 = *(const float4*)(nb + k0 + 4);
        const float nwv[8] = {a0.x,a0.y,a0.z,a0.w,a1.x,a1.y,a1.z,a1.w};
        const float nbv[8] = {c0.x,c0.y,c0.z,c0.w,c1.x,c1.y,c1.z,c1.w};
        #pragma unroll
        for (int t = 0; t < 4; ++t) {
            const int n = wave * 64 + t * 16 + m16;
            const float4* wp = (const float4*)(W + n * C_IN + k0);
            const float4 w0 = wp[0], w1 = wp[1];
            const float wvv[8] = {w0.x,w0.y,w0.z,w0.w,w1.x,w1.y,w1.z,w1.w};
            short8 b;
            #pragma unroll
            for (int j = 0; j < 8; ++j) {
                b[j] = f2bf_bits(wvv[j] * nwv[j]);
                cpart[t] += nbv[j] * wvv[j];
            }
            bfrag[t][s] = b;
        }
    }
    #pragma unroll
    for (int t = 0; t < 4; ++t) {
        cpart[t] += __shfl_xor(cpart[t], 16);
        cpart[t] += __shfl_xor(cpart[t], 32);
    }
    const float cbias = (qd == 0) ? cpart[0] : (qd == 1) ? cpart[1]
                      : (qd == 2) ? cpart[2] : cpart[3];

    const int sr = tid >> 3;
    const int sc = tid & 7;

    const int nbat = (mq + 1) / 2;
    const int g = gridDim.x;
    const int nk = mq * KNN;

    int bat = blockIdx.x;
    float4 pf[4];
    int idxn;
    {
        const int id0 = knn[min(bat * 32 + sr, nk - 1)];
        const float* xr = x + (long long)id0 * C_IN + sc * 4;
        #pragma unroll
        for (int t = 0; t < 4; ++t) pf[t] = *(const float4*)(xr + t * 32);
        const int b1 = (bat + g < nbat) ? (bat + g) : bat;
        idxn = knn[min(b1 * 32 + sr, nk - 1)];
    }

    int buf = 0;
    for (; bat < nbat; bat += g) {
        float s1 = 0.f, s2 = 0.f;
        #pragma unroll
        for (int t = 0; t < 4; ++t) {
            s1 += pf[t].x + pf[t].y + pf[t].z + pf[t].w;
            s2 += pf[t].x*pf[t].x + pf[t].y*pf[t].y + pf[t].z*pf[t].z + pf[t].w*pf[t].w;
        }
        #pragma unroll
        for (int off = 1; off < 8; off <<= 1) {
            s1 += __shfl_xor(s1, off);
            s2 += __shfl_xor(s2, off);
        }
        const float mu   = s1 * (1.f / 128.f);
        const float rstd = rsqrtf(s2 * (1.f / 128.f) - mu * mu + LN_EPS);
        #pragma unroll
        for (int t = 0; t < 4; ++t) {
            short4_t hb;
            hb[0] = f2bf_bits((pf[t].x - mu) * rstd);
            hb[1] = f2bf_bits((pf[t].y - mu) * rstd);
            hb[2] = f2bf_bits((pf[t].z - mu) * rstd);
            hb[3] = f2bf_bits((pf[t].w - mu) * rstd);
            const int pb = ((sc >> 1) + 4 * t) ^ (sr & 15);
            *(short4_t*)&Ash[buf * 4096 + sr * 128 + pb * 8 + (sc & 1) * 4] = hb;
        }
        __syncthreads();

        if (bat + g < nbat) {
            const float* xr = x + (long long)idxn * C_IN + sc * 4;
            #pragma unroll
            for (int t = 0; t < 4; ++t) pf[t] = *(const float4*)(xr + t * 32);
            const int b2 = (bat + 2 * g < nbat) ? (bat + 2 * g) : (bat + g);
            idxn = knn[min(b2 * 32 + sr, nk - 1)];
        }

        #pragma unroll
        for (int ql = 0; ql < 2; ++ql) {
            short8 afrag[4];
            #pragma unroll
            for (int s = 0; s < 4; ++s) {
                const int pb = (s * 4 + qd) ^ m16;
                afrag[s] = *(const short8*)&Ash[buf * 4096 + (ql * 16 + m16) * 128 + pb * 8];
            }
            f32x4 acc[4] = {{0,0,0,0},{0,0,0,0},{0,0,0,0},{0,0,0,0}};
            #pragma unroll
            for (int s = 0; s < 4; ++s) {
                const bf16x8 av = __builtin_bit_cast(bf16x8, afrag[s]);
                #pragma unroll
                for (int t = 0; t < 4; ++t)
                    acc[t] = __builtin_amdgcn_mfma_f32_16x16x32_bf16(
                        av, __builtin_bit_cast(bf16x8, bfrag[t][s]), acc[t], 0, 0, 0);
            }
            float r[4];
            #pragma unroll
            for (int t = 0; t < 4; ++t) {
                float v = fmaxf(fmaxf(acc[t][0], acc[t][1]), fmaxf(acc[t][2], acc[t][3]));
                v = fmaxf(v, __shfl_xor(v, 16));
                v = fmaxf(v, __shfl_xor(v, 32));
                r[t] = v;
            }
            const float vout = ((qd == 0) ? r[0] : (qd == 1) ? r[1]
                              : (qd == 2) ? r[2] : r[3]) + cbias;
            const int q = bat * 2 + ql;
            if (q < mq) out[q * C_OUT + wave * 64 + lane] = vout;
        }
        buf ^= 1;
    }

    const int gtid = blockIdx.x * 256 + tid;
    const int gstr = g * 256;
    const int np4 = npcnt >> 2;
    for (int i = gtid; i < np4; i += gstr)
        ((float4*)out_np)[i] = ((const float4*)n_p)[i];
    for (int i = (np4 << 2) + gtid; i < npcnt; i += gstr) out_np[i] = n_p[i];
    if (gtid < 4) out_no[gtid] = (float)n_o[gtid];
}

extern "C" void kernel_launch(void* const* d_in, const int* in_sizes, int n_in,
                              void* d_out, int out_size, void* d_ws, size_t ws_size,
                              hipStream_t stream)
{
    const float* x   = (const float*)d_in[1];
    const float* n_p = (const float*)d_in[3];
    const int*   knn = (const int*)  d_in[4];
    const int*   n_o = (const int*)  d_in[5];
    const float* nw  = (const float*)d_in[6];
    const float* nb  = (const float*)d_in[7];
    const float* W   = (const float*)d_in[8];
    float* out = (float*)d_out;

    // in_sizes are ELEMENT counts (mq = in_sizes[4]/16 = 50000 proves it).
    const int n     = in_sizes[1] / C_IN;   // 200000 source rows
    const int mq    = in_sizes[4] / KNN;    // 50000
    const int npcnt = in_sizes[3];          // 150000
    float* out_np = out + (size_t)mq * C_OUT;
    float* out_no = out_np + npcnt;

    const size_t ws_need = (size_t)n * BROW;   // 25.6 MB fp8 table
    if (ws_size >= ws_need) {
        unsigned* xq = (unsigned*)d_ws;
        const int nbat = (mq + BQ - 1) / BQ;
        const int grid = (nbat < NBLK) ? nbat : NBLK;
        hipLaunchKernelGGL(lnq_kernel, dim3((n + 7) / 8), dim3(256), 0, stream,
                           x, xq, n);
        if (mq % BQ == 0) {
            hipLaunchKernelGGL(fused_gather_kernel<true>, dim3(grid), dim3(BLOCK), 0,
                               stream, (const unsigned char*)xq, knn, nw, nb, W,
                               n_p, n_o, out, out_np, out_no, mq, npcnt);
        } else {
            hipLaunchKernelGGL(fused_gather_kernel<false>, dim3(grid), dim3(BLOCK), 0,
                               stream, (const unsigned char*)xq, knn, nw, nb, W,
                               n_p, n_o, out, out_np, out_no, mq, npcnt);
        }
    } else {
        hipLaunchKernelGGL(fused_inline_kernel, dim3(NBLK), dim3(256), 0, stream,
                           x, knn, nw, nb, W, n_p, n_o, out, out_np, out_no, mq, npcnt);
    }
}

// Round 7
// 243.616 us; speedup vs baseline: 1.0739x; 1.0119x over previous
//
#include <hip/hip_runtime.h>

// DownSample fused: gather(knn) -> LayerNorm(C=128) -> Linear(128->256, MFMA) -> maxpool(k=16)
// Outputs concatenated: out[m,256] f32 | n_p[m,3] f32 | n_o[4] as f32
//
// R11: fused reverted to the PROVEN R8 kernel verbatim (74.5us best measured).
//   R10's addressing hoist cut VALU ~15% but wall was flat/worse -- gather
//   service rate (800k row-requests / ~75us, byte-size-invariant) is the wall,
//   so VALU polish is dead weight. R8 is the known-good config.
// lnq v2 (the one experiment this round): was ~36-45us vs 23us traffic floor.
//   - 16 lanes/row, two stride-256B float4 loads (each instr fully coalesced)
//   - 4 shuffle rounds (16-lane reduce), coalesced 4B stores
//   - grid-stride, 2048 blocks (8/CU) instead of 25k one-shot blocks
// Fallback (ws too small): R4 single-pass bf16 kernel, verbatim.

#define C_IN   128
#define C_OUT  256
#define KNN    16
#define LN_EPS 1e-5f
#define BQ     4
#define ROWS   (BQ * KNN)       // 64
#define WAVES  8
#define BLOCK  (WAVES * 64)     // 512
#define NBLK   1024
#define BROW   128              // bytes per fp8 row
#define BUFB   (ROWS * BROW)    // 8 KB per buffer
#define BSCL   16.0f
#define IBSCL  (1.0f / 16.0f)

typedef __attribute__((ext_vector_type(8))) short  short8;
typedef __attribute__((ext_vector_type(4))) short  short4_t;
typedef __attribute__((ext_vector_type(8))) __bf16 bf16x8;
typedef __attribute__((ext_vector_type(4))) float  f32x4;

__device__ __forceinline__ short f2bf_bits(float f) {
    unsigned u = __float_as_uint(f);
    u += 0x7fffu + ((u >> 16) & 1u);   // round-to-nearest-even
    return (short)(u >> 16);
}

// ---- fp8 e4m3 (OCP) packing: 2 floats -> 2 bytes in low/high half of a u32 ----
#if defined(__has_builtin) && __has_builtin(__builtin_amdgcn_cvt_pk_fp8_f32)
__device__ __forceinline__ unsigned pk2fp8(float a, float b, unsigned old, bool hi) {
    return hi ? (unsigned)__builtin_amdgcn_cvt_pk_fp8_f32(a, b, (int)old, true)
              : (unsigned)__builtin_amdgcn_cvt_pk_fp8_f32(a, b, (int)old, false);
}
#else
__device__ __forceinline__ unsigned fp8e4m3_byte(float f) {
    unsigned u = __float_as_uint(f);
    const unsigned sgn = (u >> 24) & 0x80u;
    const float af = __uint_as_float(u & 0x7fffffffu);
    if (!(af < 448.f)) return sgn | 0x7Eu;          // saturate
    if (af < 0.015625f) {                           // subnormal: q * 2^-9
        int q = (int)(af * 512.f + 0.5f);
        return (q > 7) ? (sgn | 0x08u) : (sgn | (unsigned)q);
    }
    unsigned au = u & 0x7fffffffu;
    au += 0x7FFFFu + ((au >> 20) & 1u);             // RNE to 3 mantissa bits
    const int e = (int)(au >> 23) - 127;
    if (e > 8) return sgn | 0x7Eu;
    return sgn | ((unsigned)(e + 7) << 3) | ((au >> 20) & 7u);
}
__device__ __forceinline__ unsigned pk2fp8(float a, float b, unsigned old, bool hi) {
    const unsigned p = fp8e4m3_byte(a) | (fp8e4m3_byte(b) << 8);
    return hi ? ((old & 0xffffu) | (p << 16)) : ((old & 0xffff0000u) | p);
}
#endif

__device__ __forceinline__ void gl_lds16b(const void* src, void* dst) {
    __builtin_amdgcn_global_load_lds(
        (const __attribute__((address_space(1))) void*)src,
        (__attribute__((address_space(3))) void*)dst, 16, 0, 0);
}

// ---------------------------------------------------------------------------
// Pass A v2: LayerNorm(x[n,128]) -> fp8 e4m3 rows. 16 lanes/row, two
// stride-256B float4 loads per lane (each instr contiguous), 4-round
// 16-lane shuffle reduce, coalesced 4B stores. Grid-stride.
// ---------------------------------------------------------------------------
__global__ __launch_bounds__(256) void lnq_kernel(
    const float* __restrict__ x, unsigned* __restrict__ xq, int n)
{
    const int c    = threadIdx.x & 15;              // chunk lane within row
    const int rstp = gridDim.x * 16;                // rows per grid pass
    for (int r = blockIdx.x * 16 + (threadIdx.x >> 4); r < n; r += rstp) {
        const float* xr = x + (long long)r * C_IN;
        const float4 v0 = *(const float4*)(xr + c * 4);        // floats [c*4, c*4+4)
        const float4 v1 = *(const float4*)(xr + 64 + c * 4);   // floats [64+c*4, ...)
        float s1 = v0.x + v0.y + v0.z + v0.w + v1.x + v1.y + v1.z + v1.w;
        float s2 = v0.x*v0.x + v0.y*v0.y + v0.z*v0.z + v0.w*v0.w
                 + v1.x*v1.x + v1.y*v1.y + v1.z*v1.z + v1.w*v1.w;
        #pragma unroll
        for (int off = 1; off < 16; off <<= 1) {
            s1 += __shfl_xor(s1, off);
            s2 += __shfl_xor(s2, off);
        }
        const float mu   = s1 * (1.f / 128.f);
        const float rstd = rsqrtf(s2 * (1.f / 128.f) - mu * mu + LN_EPS);
        unsigned p0 = pk2fp8((v0.x - mu) * rstd, (v0.y - mu) * rstd, 0u, false);
        p0 = pk2fp8((v0.z - mu) * rstd, (v0.w - mu) * rstd, p0, true);
        unsigned p1 = pk2fp8((v1.x - mu) * rstd, (v1.y - mu) * rstd, 0u, false);
        p1 = pk2fp8((v1.z - mu) * rstd, (v1.w - mu) * rstd, p1, true);
        unsigned* orow = xq + (long long)r * 32;
        orow[c]      = p0;
        orow[16 + c] = p1;
    }
}

// ---------------------------------------------------------------------------
// Pass B (R8 verbatim, proven 74.5us): gather fp8 rows -> LDS (1 DMA/wave/iter,
// source-side swizzle) -> fp8 MFMA -> maxpool -> store. One barrier / 4 queries.
// ---------------------------------------------------------------------------
__global__ __launch_bounds__(BLOCK) void fused_gather_kernel(
    const unsigned char* __restrict__ xq, const int* __restrict__ knn,
    const float* __restrict__ nw, const float* __restrict__ nb,
    const float* __restrict__ W,
    const float* __restrict__ n_p, const int* __restrict__ n_o,
    float* __restrict__ out, float* __restrict__ out_np, float* __restrict__ out_no,
    int mq, int npcnt)
{
    // 2 buffers x 64 rows x 128B. LDS 16B-block p of row r holds source block
    // p ^ (r&7) (source-side swizzle; linear DMA dest).
    __shared__ __align__(16) char Ash[2 * BUFB];   // 16 KB

    const int tid  = threadIdx.x;
    const int lane = tid & 63;
    const int wave = tid >> 6;          // wave w owns out cols [w*32, w*32+32)
    const int m16  = lane & 15;
    const int qd   = lane >> 4;

    const int g    = gridDim.x;
    const int nbat = (mq + BQ - 1) / BQ;
    const int nk   = mq * KNN;

    // Gather roles: wave w stages rows [w*8, w*8+8) via ONE global_load_lds:
    // lane l -> dest row w*8 + (l>>3), dest 16B-block l&7 (linear);
    // source block = (l&7) ^ (row&7).
    const int myrow = wave * 8 + (lane >> 3);
    const int sboff = ((lane & 7) ^ (myrow & 7)) * 16;

    int bat = blockIdx.x;
    // first batch's knn index (this lane's row), latency hidden under preamble
    int i0 = knn[min(bat * ROWS + myrow, nk - 1)];

    // ---- preamble: B frags = fp8(W[n][k]*nw[k]*16); c[n] = sum_k nb[k]W[n][k]
    long  bfr[2][4];                    // [col-tile][k-step]
    float cp0 = 0.f, cp1 = 0.f;
    #pragma unroll
    for (int s = 0; s < 4; ++s) {
        const int k0 = s * 32 + qd * 8;
        const float4 a0 = *(const float4*)(nw + k0);
        const float4 a1 = *(const float4*)(nw + k0 + 4);
        const float4 c0 = *(const float4*)(nb + k0);
        const float4 c1 = *(const float4*)(nb + k0 + 4);
        const float nwv[8] = {a0.x,a0.y,a0.z,a0.w,a1.x,a1.y,a1.z,a1.w};
        const float nbv[8] = {c0.x,c0.y,c0.z,c0.w,c1.x,c1.y,c1.z,c1.w};
        #pragma unroll
        for (int t = 0; t < 2; ++t) {
            const int n_ = wave * 32 + t * 16 + m16;
            const float4* wp = (const float4*)(W + n_ * C_IN + k0);
            const float4 w0 = wp[0], w1 = wp[1];
            const float wvv[8] = {w0.x,w0.y,w0.z,w0.w,w1.x,w1.y,w1.z,w1.w};
            float cacc = 0.f;
            #pragma unroll
            for (int j = 0; j < 8; ++j) cacc += nbv[j] * wvv[j];
            unsigned lo = pk2fp8(wvv[0]*nwv[0]*BSCL, wvv[1]*nwv[1]*BSCL, 0u, false);
            lo = pk2fp8(wvv[2]*nwv[2]*BSCL, wvv[3]*nwv[3]*BSCL, lo, true);
            unsigned hi = pk2fp8(wvv[4]*nwv[4]*BSCL, wvv[5]*nwv[5]*BSCL, 0u, false);
            hi = pk2fp8(wvv[6]*nwv[6]*BSCL, wvv[7]*nwv[7]*BSCL, hi, true);
            bfr[t][s] = (long)(((unsigned long long)hi << 32) | lo);
            if (t == 0) cp0 += cacc; else cp1 += cacc;
        }
    }
    cp0 += __shfl_xor(cp0, 16); cp0 += __shfl_xor(cp0, 32);
    cp1 += __shfl_xor(cp1, 16); cp1 += __shfl_xor(cp1, 32);

    // ---- prime pipeline: gather batch `bat` into buf0; idx for batch +g ----
    gl_lds16b(xq + (long long)i0 * BROW + sboff, Ash + wave * 1024);
    const int b1 = (bat + g < nbat) ? (bat + g) : bat;
    int inext = knn[min(b1 * ROWS + myrow, nk - 1)];

    int buf = 0;
    for (; bat < nbat; bat += g) {
        // compiler emits s_waitcnt vmcnt(0) lgkmcnt(0) before s_barrier ->
        // buf's DMA writes complete; prior iter's LDS reads drained.
        __syncthreads();

        // ---- issue next batch's gather NOW (in flight during MFMA below) ----
        if (bat + g < nbat) {
            gl_lds16b(xq + (long long)inext * BROW + sboff,
                      Ash + (buf ^ 1) * BUFB + wave * 1024);
            const int b2 = (bat + 2 * g < nbat) ? (bat + 2 * g) : (bat + g);
            inext = knn[min(b2 * ROWS + myrow, nk - 1)];
        }

        // ---- MFMA + maxpool for the 4 queries; paired 64-lane stores ----
        #pragma unroll
        for (int jp = 0; jp < 2; ++jp) {
            float ra0, ra1, rb0, rb1;
            #pragma unroll
            for (int half = 0; half < 2; ++half) {
                const int ql = jp * 2 + half;
                const int r  = ql * 16 + m16;
                long afr[4];
                #pragma unroll
                for (int s = 0; s < 4; ++s) {
                    const int pos = (s * 2 + (qd >> 1)) ^ (r & 7);
                    afr[s] = *(const long*)&Ash[buf * BUFB + r * BROW + pos * 16 + (qd & 1) * 8];
                }
                f32x4 acc0 = {0,0,0,0}, acc1 = {0,0,0,0};
                #pragma unroll
                for (int s = 0; s < 4; ++s) {
                    acc0 = __builtin_amdgcn_mfma_f32_16x16x32_fp8_fp8(
                        afr[s], bfr[0][s], acc0, 0, 0, 0);
                    acc1 = __builtin_amdgcn_mfma_f32_16x16x32_fp8_fp8(
                        afr[s], bfr[1][s], acc1, 0, 0, 0);
                }
                float v0 = fmaxf(fmaxf(acc0[0], acc0[1]), fmaxf(acc0[2], acc0[3]));
                v0 = fmaxf(v0, __shfl_xor(v0, 16));
                v0 = fmaxf(v0, __shfl_xor(v0, 32));
                float v1 = fmaxf(fmaxf(acc1[0], acc1[1]), fmaxf(acc1[2], acc1[3]));
                v1 = fmaxf(v1, __shfl_xor(v1, 16));
                v1 = fmaxf(v1, __shfl_xor(v1, 32));
                if (half == 0) { ra0 = v0; ra1 = v1; }
                else           { rb0 = v0; rb1 = v1; }
            }
            // lanes qd in {0,1}: query jp*2, lanes qd in {2,3}: query jp*2+1
            const float s0 = (qd >> 1) ? rb0 : ra0;
            const float s1 = (qd >> 1) ? rb1 : ra1;
            const float val = ((qd & 1) ? s1 : s0) * IBSCL + ((qd & 1) ? cp1 : cp0);
            const int q = bat * BQ + jp * 2 + (qd >> 1);
            if (q < mq)
                out[q * C_OUT + wave * 32 + (qd & 1) * 16 + m16] = val;
        }
        buf ^= 1;
    }

    // ---- passthrough outputs ----
    const int gtid = blockIdx.x * BLOCK + tid;
    const int gstr = g * BLOCK;
    const int np4 = npcnt >> 2;
    for (int i = gtid; i < np4; i += gstr)
        ((float4*)out_np)[i] = ((const float4*)n_p)[i];
    for (int i = (np4 << 2) + gtid; i < npcnt; i += gstr) out_np[i] = n_p[i];
    if (gtid < 4) out_no[gtid] = (float)n_o[gtid];
}

// ---------------------------------------------------------------------------
// Fallback: single-pass bf16 kernel (R4, proven) for when ws_size is too small.
// ---------------------------------------------------------------------------
__global__ __launch_bounds__(256) void fused_inline_kernel(
    const float* __restrict__ x, const int* __restrict__ knn,
    const float* __restrict__ nw, const float* __restrict__ nb,
    const float* __restrict__ W,
    const float* __restrict__ n_p, const int* __restrict__ n_o,
    float* __restrict__ out, float* __restrict__ out_np, float* __restrict__ out_no,
    int mq, int npcnt)
{
    __shared__ __align__(16) short Ash[2 * 32 * C_IN];

    const int tid  = threadIdx.x;
    const int lane = tid & 63;
    const int wave = tid >> 6;
    const int m16  = lane & 15;
    const int qd   = lane >> 4;

    short8 bfrag[4][4];
    float  cpart[4] = {0.f, 0.f, 0.f, 0.f};
    #pragma unroll
    for (int s = 0; s < 4; ++s) {
        const int k0 = s * 32 + qd * 8;
        const float4 a0 = *(const float4*)(nw + k0);
        const float4 a1 = *(const float4*)(nw + k0 + 4);
        const float4 c0 = *(const float4*)(nb + k0);
        const float4 c1 = *(const float4*)(nb + k0 + 4);
        const float nwv[8] = {a0.x,a0.y,a0.z,a0.w,a1.x,a1.y,a1.z,a1.w};
        const float nbv[8] = {c0.x,c0.y,c0.z,c0.w,c1.x,c1.y,c1.z,c1.w};
        #pragma unroll
        for (int t = 0; t < 4; ++t) {
            const int n = wave * 64 + t * 16 + m16;
            const float4* wp = (const float4*)(W + n * C_IN + k0);
            const float4 w0 = wp[0], w1 = wp[1];
            const float wvv[8] = {w0.x,w0.y,w0.z,w0.w,w1.x,w1.y,w1.z,w1.w};
            short8 b;
            #pragma unroll
            for (int j = 0; j < 8; ++j) {
                b[j] = f2bf_bits(wvv[j] * nwv[j]);
                cpart[t] += nbv[j] * wvv[j];
            }
            bfrag[t][s] = b;
        }
    }
    #pragma unroll
    for (int t = 0; t < 4; ++t) {
        cpart[t] += __shfl_xor(cpart[t], 16);
        cpart[t] += __shfl_xor(cpart[t], 32);
    }
    const float cbias = (qd == 0) ? cpart[0] : (qd == 1) ? cpart[1]
                      : (qd == 2) ? cpart[2] : cpart[3];

    const int sr = tid >> 3;
    const int sc = tid & 7;

    const int nbat = (mq + 1) / 2;
    const int g = gridDim.x;
    const int nk = mq * KNN;

    int bat = blockIdx.x;
    float4 pf[4];
    int idxn;
    {
        const int id0 = knn[min(bat * 32 + sr, nk - 1)];
        const float* xr = x + (long long)id0 * C_IN + sc * 4;
        #pragma unroll
        for (int t = 0; t < 4; ++t) pf[t] = *(const float4*)(xr + t * 32);
        const int b1 = (bat + g < nbat) ? (bat + g) : bat;
        idxn = knn[min(b1 * 32 + sr, nk - 1)];
    }

    int buf = 0;
    for (; bat < nbat; bat += g) {
        float s1 = 0.f, s2 = 0.f;
        #pragma unroll
        for (int t = 0; t < 4; ++t) {
            s1 += pf[t].x + pf[t].y + pf[t].z + pf[t].w;
            s2 += pf[t].x*pf[t].x + pf[t].y*pf[t].y + pf[t].z*pf[t].z + pf[t].w*pf[t].w;
        }
        #pragma unroll
        for (int off = 1; off < 8; off <<= 1) {
            s1 += __shfl_xor(s1, off);
            s2 += __shfl_xor(s2, off);
        }
        const float mu   = s1 * (1.f / 128.f);
        const float rstd = rsqrtf(s2 * (1.f / 128.f) - mu * mu + LN_EPS);
        #pragma unroll
        for (int t = 0; t < 4; ++t) {
            short4_t hb;
            hb[0] = f2bf_bits((pf[t].x - mu) * rstd);
            hb[1] = f2bf_bits((pf[t].y - mu) * rstd);
            hb[2] = f2bf_bits((pf[t].z - mu) * rstd);
            hb[3] = f2bf_bits((pf[t].w - mu) * rstd);
            const int pb = ((sc >> 1) + 4 * t) ^ (sr & 15);
            *(short4_t*)&Ash[buf * 4096 + sr * 128 + pb * 8 + (sc & 1) * 4] = hb;
        }
        __syncthreads();

        if (bat + g < nbat) {
            const float* xr = x + (long long)idxn * C_IN + sc * 4;
            #pragma unroll
            for (int t = 0; t < 4; ++t) pf[t] = *(const float4*)(xr + t * 32);
            const int b2 = (bat + 2 * g < nbat) ? (bat + 2 * g) : (bat + g);
            idxn = knn[min(b2 * 32 + sr, nk - 1)];
        }

        #pragma unroll
        for (int ql = 0; ql < 2; ++ql) {
            short8 afrag[4];
            #pragma unroll
            for (int s = 0; s < 4; ++s) {
                const int pb = (s * 4 + qd) ^ m16;
                afrag[s] = *(const short8*)&Ash[buf * 4096 + (ql * 16 + m16) * 128 + pb * 8];
            }
            f32x4 acc[4] = {{0,0,0,0},{0,0,0,0},{0,0,0,0},{0,0,0,0}};
            #pragma unroll
            for (int s = 0; s < 4; ++s) {
                const bf16x8 av = __builtin_bit_cast(bf16x8, afrag[s]);
                #pragma unroll
                for (int t = 0; t < 4; ++t)
                    acc[t] = __builtin_amdgcn_mfma_f32_16x16x32_bf16(
                        av, __builtin_bit_cast(bf16x8, bfrag[t][s]), acc[t], 0, 0, 0);
            }
            float r[4];
            #pragma unroll
            for (int t = 0; t < 4; ++t) {
                float v = fmaxf(fmaxf(acc[t][0], acc[t][1]), fmaxf(acc[t][2], acc[t][3]));
                v = fmaxf(v, __shfl_xor(v, 16));
                v = fmaxf(v, __shfl_xor(v, 32));
                r[t] = v;
            }
            const float vout = ((qd == 0) ? r[0] : (qd == 1) ? r[1]
                              : (qd == 2) ? r[2] : r[3]) + cbias;
            const int q = bat * 2 + ql;
            if (q < mq) out[q * C_OUT + wave * 64 + lane] = vout;
        }
        buf ^= 1;
    }

    const int gtid = blockIdx.x * 256 + tid;
    const int gstr = g * 256;
    const int np4 = npcnt >> 2;
    for (int i = gtid; i < np4; i += gstr)
        ((float4*)out_np)[i] = ((const float4*)n_p)[i];
    for (int i = (np4 << 2) + gtid; i < npcnt; i += gstr) out_np[i] = n_p[i];
    if (gtid < 4) out_no[gtid] = (float)n_o[gtid];
}

extern "C" void kernel_launch(void* const* d_in, const int* in_sizes, int n_in,
                              void* d_out, int out_size, void* d_ws, size_t ws_size,
                              hipStream_t stream)
{
    const float* x   = (const float*)d_in[1];
    const float* n_p = (const float*)d_in[3];
    const int*   knn = (const int*)  d_in[4];
    const int*   n_o = (const int*)  d_in[5];
    const float* nw  = (const float*)d_in[6];
    const float* nb  = (const float*)d_in[7];
    const float* W   = (const float*)d_in[8];
    float* out = (float*)d_out;

    // in_sizes are ELEMENT counts (mq = in_sizes[4]/16 = 50000 proves it).
    const int n     = in_sizes[1] / C_IN;   // 200000 source rows
    const int mq    = in_sizes[4] / KNN;    // 50000
    const int npcnt = in_sizes[3];          // 150000
    float* out_np = out + (size_t)mq * C_OUT;
    float* out_no = out_np + npcnt;

    const size_t ws_need = (size_t)n * BROW;   // 25.6 MB fp8 table
    if (ws_size >= ws_need) {
        unsigned* xq = (unsigned*)d_ws;
        const int ngrp = (n + 15) / 16;
        const int lgrid = (ngrp < 2048) ? ngrp : 2048;
        hipLaunchKernelGGL(lnq_kernel, dim3(lgrid), dim3(256), 0, stream,
                           x, xq, n);
        hipLaunchKernelGGL(fused_gather_kernel, dim3(NBLK), dim3(BLOCK), 0, stream,
                           (const unsigned char*)xq, knn, nw, nb, W, n_p, n_o,
                           out, out_np, out_no, mq, npcnt);
    } else {
        hipLaunchKernelGGL(fused_inline_kernel, dim3(NBLK), dim3(256), 0, stream,
                           x, knn, nw, nb, W, n_p, n_o, out, out_np, out_no, mq, npcnt);
    }
}

// Round 8
// 241.454 us; speedup vs baseline: 1.0836x; 1.0090x over previous
//
#include <hip/hip_runtime.h>

// DownSample fused: gather(knn) -> LayerNorm(C=128) -> Linear(128->256, MFMA) -> maxpool(k=16)
// Outputs concatenated: out[m,256] f32 | n_p[m,3] f32 | n_o[4] as f32
//
// R12: deep-pipelined gather (guide T3/T4). R8's __syncthreads drains vmcnt(0)
// every iter -> DMA gets <1 compute phase of cover; ~40% all-wave stall.
// Changes (compute core R8-verbatim):
//  - 4 LDS buffers (32KB); DMA issued 3 iters ahead of consumption.
//  - knn idx bulk-preloaded to LDS (4KB) -> in-loop vmem = [DMA, st, st] only.
//  - per iter: asm s_waitcnt vmcnt(4) + raw s_barrier + sched_barrier(0).
//    vmcnt(4) forces DMA(t+2) (5th from end of the uniform stream) while
//    DMA(t+3) stays in flight; correct for all t incl. prologue (enumerated).
//  - lnq reverted to proven v1 (R4/R8: 32 thr/row, best measured total).
// Fallback (ws too small): R4 single-pass bf16 kernel, verbatim.

#define C_IN   128
#define C_OUT  256
#define KNN    16
#define LN_EPS 1e-5f
#define BQ     4
#define ROWS   (BQ * KNN)       // 64
#define WAVES  8
#define BLOCK  (WAVES * 64)     // 512
#define NBLK   1024
#define BROW   128              // bytes per fp8 row
#define BUFB   (ROWS * BROW)    // 8 KB per buffer
#define NSLOT  16               // idx table slots (max iters/block + 3)
#define BSCL   16.0f
#define IBSCL  (1.0f / 16.0f)

typedef __attribute__((ext_vector_type(8))) short  short8;
typedef __attribute__((ext_vector_type(4))) short  short4_t;
typedef __attribute__((ext_vector_type(8))) __bf16 bf16x8;
typedef __attribute__((ext_vector_type(4))) float  f32x4;

__device__ __forceinline__ short f2bf_bits(float f) {
    unsigned u = __float_as_uint(f);
    u += 0x7fffu + ((u >> 16) & 1u);   // round-to-nearest-even
    return (short)(u >> 16);
}

// ---- fp8 e4m3 (OCP) packing: 2 floats -> 2 bytes in low/high half of a u32 ----
#if defined(__has_builtin) && __has_builtin(__builtin_amdgcn_cvt_pk_fp8_f32)
__device__ __forceinline__ unsigned pk2fp8(float a, float b, unsigned old, bool hi) {
    return hi ? (unsigned)__builtin_amdgcn_cvt_pk_fp8_f32(a, b, (int)old, true)
              : (unsigned)__builtin_amdgcn_cvt_pk_fp8_f32(a, b, (int)old, false);
}
#else
__device__ __forceinline__ unsigned fp8e4m3_byte(float f) {
    unsigned u = __float_as_uint(f);
    const unsigned sgn = (u >> 24) & 0x80u;
    const float af = __uint_as_float(u & 0x7fffffffu);
    if (!(af < 448.f)) return sgn | 0x7Eu;          // saturate
    if (af < 0.015625f) {                           // subnormal: q * 2^-9
        int q = (int)(af * 512.f + 0.5f);
        return (q > 7) ? (sgn | 0x08u) : (sgn | (unsigned)q);
    }
    unsigned au = u & 0x7fffffffu;
    au += 0x7FFFFu + ((au >> 20) & 1u);             // RNE to 3 mantissa bits
    const int e = (int)(au >> 23) - 127;
    if (e > 8) return sgn | 0x7Eu;
    return sgn | ((unsigned)(e + 7) << 3) | ((au >> 20) & 7u);
}
__device__ __forceinline__ unsigned pk2fp8(float a, float b, unsigned old, bool hi) {
    const unsigned p = fp8e4m3_byte(a) | (fp8e4m3_byte(b) << 8);
    return hi ? ((old & 0xffffu) | (p << 16)) : ((old & 0xffff0000u) | p);
}
#endif

__device__ __forceinline__ void gl_lds16b(const void* src, void* dst) {
    __builtin_amdgcn_global_load_lds(
        (const __attribute__((address_space(1))) void*)src,
        (__attribute__((address_space(3))) void*)dst, 16, 0, 0);
}

// ---------------------------------------------------------------------------
// Pass A (v1, proven): LayerNorm(x[n,128]) -> fp8 e4m3 rows. 32 threads/row.
// ---------------------------------------------------------------------------
__global__ __launch_bounds__(256) void lnq_kernel(
    const float* __restrict__ x, unsigned* __restrict__ xq, int n)
{
    const int r = blockIdx.x * 8 + (threadIdx.x >> 5);
    const int c = threadIdx.x & 31;
    if (r >= n) return;
    const float4 v = *(const float4*)(x + (long long)r * C_IN + c * 4);
    float s1 = v.x + v.y + v.z + v.w;
    float s2 = v.x * v.x + v.y * v.y + v.z * v.z + v.w * v.w;
    #pragma unroll
    for (int off = 1; off < 32; off <<= 1) {
        s1 += __shfl_xor(s1, off);
        s2 += __shfl_xor(s2, off);
    }
    const float mu   = s1 * (1.f / 128.f);
    const float rstd = rsqrtf(s2 * (1.f / 128.f) - mu * mu + LN_EPS);
    unsigned p = pk2fp8((v.x - mu) * rstd, (v.y - mu) * rstd, 0u, false);
    p = pk2fp8((v.z - mu) * rstd, (v.w - mu) * rstd, p, true);
    xq[(long long)r * 32 + c] = p;
}

// ---------------------------------------------------------------------------
// Pass B: 4-deep pipelined gather -> fp8 MFMA -> maxpool -> store.
// Counted vmcnt(4) + raw barrier; never vmcnt(0) in the loop.
// ---------------------------------------------------------------------------
__global__ __launch_bounds__(BLOCK) void fused_gather_kernel(
    const unsigned char* __restrict__ xq, const int* __restrict__ knn,
    const float* __restrict__ nw, const float* __restrict__ nb,
    const float* __restrict__ W,
    const float* __restrict__ n_p, const int* __restrict__ n_o,
    float* __restrict__ out, float* __restrict__ out_np, float* __restrict__ out_no,
    int mq, int npcnt)
{
    // 4 buffers x 64 rows x 128B. LDS 16B-block p of row r holds source block
    // p ^ (r&7) (source-side swizzle; linear DMA dest). Layout as R8.
    __shared__ __align__(16) char Ash[4 * BUFB];   // 32 KB
    __shared__ int idx_lds[NSLOT * ROWS];          // 4 KB

    const int tid  = threadIdx.x;
    const int lane = tid & 63;
    const int wave = tid >> 6;          // wave w owns out cols [w*32, w*32+32)
    const int m16  = lane & 15;
    const int qd   = lane >> 4;

    const int g    = gridDim.x;
    const int nbat = (mq + BQ - 1) / BQ;
    const int nk   = mq * KNN;

    // Gather roles: wave w stages rows [w*8, w*8+8) via ONE global_load_lds.
    const int myrow = wave * 8 + (lane >> 3);
    const int sboff = ((lane & 7) ^ (myrow & 7)) * 16;
    char* const dwave = Ash + wave * 1024;          // + bufsel*BUFB

    // ---- bulk-preload this block's knn indices (clamped) into LDS ----
    for (int j = tid; j < NSLOT * ROWS; j += BLOCK) {
        const long long bb = (long long)blockIdx.x + (long long)(j >> 6) * g;
        const int bidx = (bb < nbat) ? (int)bb : (nbat - 1);
        idx_lds[j] = knn[min(bidx * ROWS + (j & 63), nk - 1)];
    }

    // ---- preamble: B frags = fp8(W[n][k]*nw[k]*16); c[n] = sum_k nb[k]W[n][k]
    long  bfr[2][4];                    // [col-tile][k-step]
    float cp0 = 0.f, cp1 = 0.f;
    #pragma unroll
    for (int s = 0; s < 4; ++s) {
        const int k0 = s * 32 + qd * 8;
        const float4 a0 = *(const float4*)(nw + k0);
        const float4 a1 = *(const float4*)(nw + k0 + 4);
        const float4 c0 = *(const float4*)(nb + k0);
        const float4 c1 = *(const float4*)(nb + k0 + 4);
        const float nwv[8] = {a0.x,a0.y,a0.z,a0.w,a1.x,a1.y,a1.z,a1.w};
        const float nbv[8] = {c0.x,c0.y,c0.z,c0.w,c1.x,c1.y,c1.z,c1.w};
        #pragma unroll
        for (int t = 0; t < 2; ++t) {
            const int n_ = wave * 32 + t * 16 + m16;
            const float4* wp = (const float4*)(W + n_ * C_IN + k0);
            const float4 w0 = wp[0], w1 = wp[1];
            const float wvv[8] = {w0.x,w0.y,w0.z,w0.w,w1.x,w1.y,w1.z,w1.w};
            float cacc = 0.f;
            #pragma unroll
            for (int j = 0; j < 8; ++j) cacc += nbv[j] * wvv[j];
            unsigned lo = pk2fp8(wvv[0]*nwv[0]*BSCL, wvv[1]*nwv[1]*BSCL, 0u, false);
            lo = pk2fp8(wvv[2]*nwv[2]*BSCL, wvv[3]*nwv[3]*BSCL, lo, true);
            unsigned hi = pk2fp8(wvv[4]*nwv[4]*BSCL, wvv[5]*nwv[5]*BSCL, 0u, false);
            hi = pk2fp8(wvv[6]*nwv[6]*BSCL, wvv[7]*nwv[7]*BSCL, hi, true);
            bfr[t][s] = (long)(((unsigned long long)hi << 32) | lo);
            if (t == 0) cp0 += cacc; else cp1 += cacc;
        }
    }
    cp0 += __shfl_xor(cp0, 16); cp0 += __shfl_xor(cp0, 32);
    cp1 += __shfl_xor(cp1, 16); cp1 += __shfl_xor(cp1, 32);

    __syncthreads();   // idx_lds visible to all; drains all preamble vmem

    // ---- prologue: issue DMAs for slots 0..2; prefetch idx for slot 3 ----
    {
        const int i0 = idx_lds[0 * ROWS + myrow];
        const int i1 = idx_lds[1 * ROWS + myrow];
        const int i2 = idx_lds[2 * ROWS + myrow];
        gl_lds16b(xq + (((long long)i0) << 7) + sboff, dwave + 0 * BUFB);
        gl_lds16b(xq + (((long long)i1) << 7) + sboff, dwave + 1 * BUFB);
        gl_lds16b(xq + (((long long)i2) << 7) + sboff, dwave + 2 * BUFB);
    }
    int nextidx = idx_lds[3 * ROWS + myrow];
    asm volatile("s_waitcnt vmcnt(2)" ::: "memory");   // DMA0 done; DMA1,2 in flight
    __builtin_amdgcn_s_barrier();
    __builtin_amdgcn_sched_barrier(0);

    const int L = (nbat - 1 - blockIdx.x) / g + 1;     // iters for this block
    for (int t = 0; t < L; ++t) {
        const int bat = blockIdx.x + t * g;

        // ---- issue DMA for slot t+3 (content clamped-valid); prefetch idx ----
        gl_lds16b(xq + (((long long)nextidx) << 7) + sboff,
                  dwave + ((t + 3) & 3) * BUFB);
        const int ns = (t + 4 < NSLOT) ? (t + 4) : (NSLOT - 1);
        nextidx = idx_lds[ns * ROWS + myrow];

        const char* Ab = Ash + (t & 3) * BUFB;

        // ---- MFMA + maxpool for the 4 queries; paired 64-lane stores ----
        #pragma unroll
        for (int jp = 0; jp < 2; ++jp) {
            float ra0, ra1, rb0, rb1;
            #pragma unroll
            for (int half = 0; half < 2; ++half) {
                const int ql = jp * 2 + half;
                const int r  = ql * 16 + m16;
                long afr[4];
                #pragma unroll
                for (int s = 0; s < 4; ++s) {
                    const int pos = (s * 2 + (qd >> 1)) ^ (r & 7);
                    afr[s] = *(const long*)(Ab + r * BROW + pos * 16 + (qd & 1) * 8);
                }
                f32x4 acc0 = {0,0,0,0}, acc1 = {0,0,0,0};
                #pragma unroll
                for (int s = 0; s < 4; ++s) {
                    acc0 = __builtin_amdgcn_mfma_f32_16x16x32_fp8_fp8(
                        afr[s], bfr[0][s], acc0, 0, 0, 0);
                    acc1 = __builtin_amdgcn_mfma_f32_16x16x32_fp8_fp8(
                        afr[s], bfr[1][s], acc1, 0, 0, 0);
                }
                float v0 = fmaxf(fmaxf(acc0[0], acc0[1]), fmaxf(acc0[2], acc0[3]));
                v0 = fmaxf(v0, __shfl_xor(v0, 16));
                v0 = fmaxf(v0, __shfl_xor(v0, 32));
                float v1 = fmaxf(fmaxf(acc1[0], acc1[1]), fmaxf(acc1[2], acc1[3]));
                v1 = fmaxf(v1, __shfl_xor(v1, 16));
                v1 = fmaxf(v1, __shfl_xor(v1, 32));
                if (half == 0) { ra0 = v0; ra1 = v1; }
                else           { rb0 = v0; rb1 = v1; }
            }
            // lanes qd in {0,1}: query jp*2, lanes qd in {2,3}: query jp*2+1
            const float s0 = (qd >> 1) ? rb0 : ra0;
            const float s1 = (qd >> 1) ? rb1 : ra1;
            const float val = ((qd & 1) ? s1 : s0) * IBSCL + ((qd & 1) ? cp1 : cp0);
            const int q = bat * BQ + jp * 2 + (qd >> 1);
            if (q < mq)
                out[q * C_OUT + wave * 32 + (qd & 1) * 16 + m16] = val;
        }

        // ---- counted drain: DMA(t+2) forced complete, DMA(t+3) in flight ----
        asm volatile("s_waitcnt vmcnt(4)" ::: "memory");
        __builtin_amdgcn_s_barrier();
        __builtin_amdgcn_sched_barrier(0);
    }

    // ---- passthrough outputs ----
    const int gtid = blockIdx.x * BLOCK + tid;
    const int gstr = g * BLOCK;
    const int np4 = npcnt >> 2;
    for (int i = gtid; i < np4; i += gstr)
        ((float4*)out_np)[i] = ((const float4*)n_p)[i];
    for (int i = (np4 << 2) + gtid; i < npcnt; i += gstr) out_np[i] = n_p[i];
    if (gtid < 4) out_no[gtid] = (float)n_o[gtid];
}

// ---------------------------------------------------------------------------
// Fallback: single-pass bf16 kernel (R4, proven) for when ws_size is too small.
// ---------------------------------------------------------------------------
__global__ __launch_bounds__(256) void fused_inline_kernel(
    const float* __restrict__ x, const int* __restrict__ knn,
    const float* __restrict__ nw, const float* __restrict__ nb,
    const float* __restrict__ W,
    const float* __restrict__ n_p, const int* __restrict__ n_o,
    float* __restrict__ out, float* __restrict__ out_np, float* __restrict__ out_no,
    int mq, int npcnt)
{
    __shared__ __align__(16) short Ash[2 * 32 * C_IN];

    const int tid  = threadIdx.x;
    const int lane = tid & 63;
    const int wave = tid >> 6;
    const int m16  = lane & 15;
    const int qd   = lane >> 4;

    short8 bfrag[4][4];
    float  cpart[4] = {0.f, 0.f, 0.f, 0.f};
    #pragma unroll
    for (int s = 0; s < 4; ++s) {
        const int k0 = s * 32 + qd * 8;
        const float4 a0 = *(const float4*)(nw + k0);
        const float4 a1 = *(const float4*)(nw + k0 + 4);
        const float4 c0 = *(const float4*)(nb + k0);
        const float4 c1 = *(const float4*)(nb + k0 + 4);
        const float nwv[8] = {a0.x,a0.y,a0.z,a0.w,a1.x,a1.y,a1.z,a1.w};
        const float nbv[8] = {c0.x,c0.y,c0.z,c0.w,c1.x,c1.y,c1.z,c1.w};
        #pragma unroll
        for (int t = 0; t < 4; ++t) {
            const int n = wave * 64 + t * 16 + m16;
            const float4* wp = (const float4*)(W + n * C_IN + k0);
            const float4 w0 = wp[0], w1 = wp[1];
            const float wvv[8] = {w0.x,w0.y,w0.z,w0.w,w1.x,w1.y,w1.z,w1.w};
            short8 b;
            #pragma unroll
            for (int j = 0; j < 8; ++j) {
                b[j] = f2bf_bits(wvv[j] * nwv[j]);
                cpart[t] += nbv[j] * wvv[j];
            }
            bfrag[t][s] = b;
        }
    }
    #pragma unroll
    for (int t = 0; t < 4; ++t) {
        cpart[t] += __shfl_xor(cpart[t], 16);
        cpart[t] += __shfl_xor(cpart[t], 32);
    }
    const float cbias = (qd == 0) ? cpart[0] : (qd == 1) ? cpart[1]
                      : (qd == 2) ? cpart[2] : cpart[3];

    const int sr = tid >> 3;
    const int sc = tid & 7;

    const int nbat = (mq + 1) / 2;
    const int g = gridDim.x;
    const int nk = mq * KNN;

    int bat = blockIdx.x;
    float4 pf[4];
    int idxn;
    {
        const int id0 = knn[min(bat * 32 + sr, nk - 1)];
        const float* xr = x + (long long)id0 * C_IN + sc * 4;
        #pragma unroll
        for (int t = 0; t < 4; ++t) pf[t] = *(const float4*)(xr + t * 32);
        const int b1 = (bat + g < nbat) ? (bat + g) : bat;
        idxn = knn[min(b1 * 32 + sr, nk - 1)];
    }

    int buf = 0;
    for (; bat < nbat; bat += g) {
        float s1 = 0.f, s2 = 0.f;
        #pragma unroll
        for (int t = 0; t < 4; ++t) {
            s1 += pf[t].x + pf[t].y + pf[t].z + pf[t].w;
            s2 += pf[t].x*pf[t].x + pf[t].y*pf[t].y + pf[t].z*pf[t].z + pf[t].w*pf[t].w;
        }
        #pragma unroll
        for (int off = 1; off < 8; off <<= 1) {
            s1 += __shfl_xor(s1, off);
            s2 += __shfl_xor(s2, off);
        }
        const float mu   = s1 * (1.f / 128.f);
        const float rstd = rsqrtf(s2 * (1.f / 128.f) - mu * mu + LN_EPS);
        #pragma unroll
        for (int t = 0; t < 4; ++t) {
            short4_t hb;
            hb[0] = f2bf_bits((pf[t].x - mu) * rstd);
            hb[1] = f2bf_bits((pf[t].y - mu) * rstd);
            hb[2] = f2bf_bits((pf[t].z - mu) * rstd);
            hb[3] = f2bf_bits((pf[t].w - mu) * rstd);
            const int pb = ((sc >> 1) + 4 * t) ^ (sr & 15);
            *(short4_t*)&Ash[buf * 4096 + sr * 128 + pb * 8 + (sc & 1) * 4] = hb;
        }
        __syncthreads();

        if (bat + g < nbat) {
            const float* xr = x + (long long)idxn * C_IN + sc * 4;
            #pragma unroll
            for (int t = 0; t < 4; ++t) pf[t] = *(const float4*)(xr + t * 32);
            const int b2 = (bat + 2 * g < nbat) ? (bat + 2 * g) : (bat + g);
            idxn = knn[min(b2 * 32 + sr, nk - 1)];
        }

        #pragma unroll
        for (int ql = 0; ql < 2; ++ql) {
            short8 afrag[4];
            #pragma unroll
            for (int s = 0; s < 4; ++s) {
                const int pb = (s * 4 + qd) ^ m16;
                afrag[s] = *(const short8*)&Ash[buf * 4096 + (ql * 16 + m16) * 128 + pb * 8];
            }
            f32x4 acc[4] = {{0,0,0,0},{0,0,0,0},{0,0,0,0},{0,0,0,0}};
            #pragma unroll
            for (int s = 0; s < 4; ++s) {
                const bf16x8 av = __builtin_bit_cast(bf16x8, afrag[s]);
                #pragma unroll
                for (int t = 0; t < 4; ++t)
                    acc[t] = __builtin_amdgcn_mfma_f32_16x16x32_bf16(
                        av, __builtin_bit_cast(bf16x8, bfrag[t][s]), acc[t], 0, 0, 0);
            }
            float r[4];
            #pragma unroll
            for (int t = 0; t < 4; ++t) {
                float v = fmaxf(fmaxf(acc[t][0], acc[t][1]), fmaxf(acc[t][2], acc[t][3]));
                v = fmaxf(v, __shfl_xor(v, 16));
                v = fmaxf(v, __shfl_xor(v, 32));
                r[t] = v;
            }
            const float vout = ((qd == 0) ? r[0] : (qd == 1) ? r[1]
                              : (qd == 2) ? r[2] : r[3]) + cbias;
            const int q = bat * 2 + ql;
            if (q < mq) out[q * C_OUT + wave * 64 + lane] = vout;
        }
        buf ^= 1;
    }

    const int gtid = blockIdx.x * 256 + tid;
    const int gstr = g * 256;
    const int np4 = npcnt >> 2;
    for (int i = gtid; i < np4; i += gstr)
        ((float4*)out_np)[i] = ((const float4*)n_p)[i];
    for (int i = (np4 << 2) + gtid; i < npcnt; i += gstr) out_np[i] = n_p[i];
    if (gtid < 4) out_no[gtid] = (float)n_o[gtid];
}

extern "C" void kernel_launch(void* const* d_in, const int* in_sizes, int n_in,
                              void* d_out, int out_size, void* d_ws, size_t ws_size,
                              hipStream_t stream)
{
    const float* x   = (const float*)d_in[1];
    const float* n_p = (const float*)d_in[3];
    const int*   knn = (const int*)  d_in[4];
    const int*   n_o = (const int*)  d_in[5];
    const float* nw  = (const float*)d_in[6];
    const float* nb  = (const float*)d_in[7];
    const float* W   = (const float*)d_in[8];
    float* out = (float*)d_out;

    // in_sizes are ELEMENT counts (mq = in_sizes[4]/16 = 50000 proves it).
    const int n     = in_sizes[1] / C_IN;   // 200000 source rows
    const int mq    = in_sizes[4] / KNN;    // 50000
    const int npcnt = in_sizes[3];          // 150000
    float* out_np = out + (size_t)mq * C_OUT;
    float* out_no = out_np + npcnt;

    const size_t ws_need = (size_t)n * BROW;   // 25.6 MB fp8 table
    if (ws_size >= ws_need) {
        unsigned* xq = (unsigned*)d_ws;
        const int nbat = (mq + BQ - 1) / BQ;
        int grid = (nbat < NBLK) ? nbat : NBLK;
        // NSLOT idx table must cover ceil(nbat/grid)+3 slots
        while ((nbat + grid - 1) / grid + 3 > NSLOT) grid *= 2;  // (never triggers here)
        hipLaunchKernelGGL(lnq_kernel, dim3((n + 7) / 8), dim3(256), 0, stream,
                           x, xq, n);
        hipLaunchKernelGGL(fused_gather_kernel, dim3(grid), dim3(BLOCK), 0, stream,
                           (const unsigned char*)xq, knn, nw, nb, W, n_p, n_o,
                           out, out_np, out_no, mq, npcnt);
    } else {
        hipLaunchKernelGGL(fused_inline_kernel, dim3(NBLK), dim3(256), 0, stream,
                           x, knn, nw, nb, W, n_p, n_o, out, out_np, out_no, mq, npcnt);
    }
}

// Round 9
// 236.436 us; speedup vs baseline: 1.1066x; 1.0212x over previous
//
#include <hip/hip_runtime.h>

// DownSample fused: gather(knn) -> LayerNorm(C=128) -> Linear(128->256, MFMA) -> maxpool(k=16)
// Outputs concatenated: out[m,256] f32 | n_p[m,3] f32 | n_o[4] as f32
//
// R13: FINAL restoration to the best-measured configuration (R4 bench: 236.7us
// total, fused 74.5us). Falsification record for the fused gather wall
// (800k random 128B rows / ~75us ~= 4.5 rows/cyc chip-wide):
//   waves (R7 flat), bytes (R8 -3us), VALU (R10 flat), pipeline depth
//   (R12 flat with vmcnt(4) 3-deep). In-flight >> latency*BW -> HW random-
//   access throughput wall. MFMA floor 21us; lnq ~40us vs 26us traffic floor.
// Structure: lnq v1 (LN->fp8 e4m3 table, 32thr/row) + R8 fused (1 DMA/wave/iter
// source-swizzled global_load_lds, fp8 MFMA, 1 barrier / 4 queries).
// Fallback (ws too small): R4 single-pass bf16 kernel, verbatim.

#define C_IN   128
#define C_OUT  256
#define KNN    16
#define LN_EPS 1e-5f
#define BQ     4
#define ROWS   (BQ * KNN)       // 64
#define WAVES  8
#define BLOCK  (WAVES * 64)     // 512
#define NBLK   1024
#define BROW   128              // bytes per fp8 row
#define BUFB   (ROWS * BROW)    // 8 KB per buffer
#define BSCL   16.0f
#define IBSCL  (1.0f / 16.0f)

typedef __attribute__((ext_vector_type(8))) short  short8;
typedef __attribute__((ext_vector_type(4))) short  short4_t;
typedef __attribute__((ext_vector_type(8))) __bf16 bf16x8;
typedef __attribute__((ext_vector_type(4))) float  f32x4;

__device__ __forceinline__ short f2bf_bits(float f) {
    unsigned u = __float_as_uint(f);
    u += 0x7fffu + ((u >> 16) & 1u);   // round-to-nearest-even
    return (short)(u >> 16);
}

// ---- fp8 e4m3 (OCP) packing: 2 floats -> 2 bytes in low/high half of a u32 ----
#if defined(__has_builtin) && __has_builtin(__builtin_amdgcn_cvt_pk_fp8_f32)
__device__ __forceinline__ unsigned pk2fp8(float a, float b, unsigned old, bool hi) {
    return hi ? (unsigned)__builtin_amdgcn_cvt_pk_fp8_f32(a, b, (int)old, true)
              : (unsigned)__builtin_amdgcn_cvt_pk_fp8_f32(a, b, (int)old, false);
}
#else
__device__ __forceinline__ unsigned fp8e4m3_byte(float f) {
    unsigned u = __float_as_uint(f);
    const unsigned sgn = (u >> 24) & 0x80u;
    const float af = __uint_as_float(u & 0x7fffffffu);
    if (!(af < 448.f)) return sgn | 0x7Eu;          // saturate
    if (af < 0.015625f) {                           // subnormal: q * 2^-9
        int q = (int)(af * 512.f + 0.5f);
        return (q > 7) ? (sgn | 0x08u) : (sgn | (unsigned)q);
    }
    unsigned au = u & 0x7fffffffu;
    au += 0x7FFFFu + ((au >> 20) & 1u);             // RNE to 3 mantissa bits
    const int e = (int)(au >> 23) - 127;
    if (e > 8) return sgn | 0x7Eu;
    return sgn | ((unsigned)(e + 7) << 3) | ((au >> 20) & 7u);
}
__device__ __forceinline__ unsigned pk2fp8(float a, float b, unsigned old, bool hi) {
    const unsigned p = fp8e4m3_byte(a) | (fp8e4m3_byte(b) << 8);
    return hi ? ((old & 0xffffu) | (p << 16)) : ((old & 0xffff0000u) | p);
}
#endif

__device__ __forceinline__ void gl_lds16b(const void* src, void* dst) {
    __builtin_amdgcn_global_load_lds(
        (const __attribute__((address_space(1))) void*)src,
        (__attribute__((address_space(3))) void*)dst, 16, 0, 0);
}

// ---------------------------------------------------------------------------
// Pass A: LayerNorm(x[n,128]) -> fp8 e4m3 rows in workspace. 32 threads/row.
// ---------------------------------------------------------------------------
__global__ __launch_bounds__(256) void lnq_kernel(
    const float* __restrict__ x, unsigned* __restrict__ xq, int n)
{
    const int r = blockIdx.x * 8 + (threadIdx.x >> 5);
    const int c = threadIdx.x & 31;
    if (r >= n) return;
    const float4 v = *(const float4*)(x + (long long)r * C_IN + c * 4);
    float s1 = v.x + v.y + v.z + v.w;
    float s2 = v.x * v.x + v.y * v.y + v.z * v.z + v.w * v.w;
    #pragma unroll
    for (int off = 1; off < 32; off <<= 1) {
        s1 += __shfl_xor(s1, off);
        s2 += __shfl_xor(s2, off);
    }
    const float mu   = s1 * (1.f / 128.f);
    const float rstd = rsqrtf(s2 * (1.f / 128.f) - mu * mu + LN_EPS);
    unsigned p = pk2fp8((v.x - mu) * rstd, (v.y - mu) * rstd, 0u, false);
    p = pk2fp8((v.z - mu) * rstd, (v.w - mu) * rstd, p, true);
    xq[(long long)r * 32 + c] = p;
}

// ---------------------------------------------------------------------------
// Pass B: gather fp8 rows -> LDS (1 DMA/wave/iter, source-side swizzle)
//         -> fp8 MFMA -> maxpool -> store. One barrier per 4 queries.
// ---------------------------------------------------------------------------
__global__ __launch_bounds__(BLOCK) void fused_gather_kernel(
    const unsigned char* __restrict__ xq, const int* __restrict__ knn,
    const float* __restrict__ nw, const float* __restrict__ nb,
    const float* __restrict__ W,
    const float* __restrict__ n_p, const int* __restrict__ n_o,
    float* __restrict__ out, float* __restrict__ out_np, float* __restrict__ out_no,
    int mq, int npcnt)
{
    // 2 buffers x 64 rows x 128B. LDS 16B-block p of row r holds source block
    // p ^ (r&7) (source-side swizzle; linear DMA dest).
    __shared__ __align__(16) char Ash[2 * BUFB];   // 16 KB

    const int tid  = threadIdx.x;
    const int lane = tid & 63;
    const int wave = tid >> 6;          // wave w owns out cols [w*32, w*32+32)
    const int m16  = lane & 15;
    const int qd   = lane >> 4;

    const int g    = gridDim.x;
    const int nbat = (mq + BQ - 1) / BQ;
    const int nk   = mq * KNN;

    // Gather roles: wave w stages rows [w*8, w*8+8) via ONE global_load_lds:
    // lane l -> dest row w*8 + (l>>3), dest 16B-block l&7 (linear);
    // source block = (l&7) ^ (row&7).
    const int myrow = wave * 8 + (lane >> 3);
    const int sboff = ((lane & 7) ^ (myrow & 7)) * 16;

    int bat = blockIdx.x;
    // first batch's knn index (this lane's row), latency hidden under preamble
    int i0 = knn[min(bat * ROWS + myrow, nk - 1)];

    // ---- preamble: B frags = fp8(W[n][k]*nw[k]*16); c[n] = sum_k nb[k]W[n][k]
    long  bfr[2][4];                    // [col-tile][k-step]
    float cp0 = 0.f, cp1 = 0.f;
    #pragma unroll
    for (int s = 0; s < 4; ++s) {
        const int k0 = s * 32 + qd * 8;
        const float4 a0 = *(const float4*)(nw + k0);
        const float4 a1 = *(const float4*)(nw + k0 + 4);
        const float4 c0 = *(const float4*)(nb + k0);
        const float4 c1 = *(const float4*)(nb + k0 + 4);
        const float nwv[8] = {a0.x,a0.y,a0.z,a0.w,a1.x,a1.y,a1.z,a1.w};
        const float nbv[8] = {c0.x,c0.y,c0.z,c0.w,c1.x,c1.y,c1.z,c1.w};
        #pragma unroll
        for (int t = 0; t < 2; ++t) {
            const int n_ = wave * 32 + t * 16 + m16;
            const float4* wp = (const float4*)(W + n_ * C_IN + k0);
            const float4 w0 = wp[0], w1 = wp[1];
            const float wvv[8] = {w0.x,w0.y,w0.z,w0.w,w1.x,w1.y,w1.z,w1.w};
            float cacc = 0.f;
            #pragma unroll
            for (int j = 0; j < 8; ++j) cacc += nbv[j] * wvv[j];
            unsigned lo = pk2fp8(wvv[0]*nwv[0]*BSCL, wvv[1]*nwv[1]*BSCL, 0u, false);
            lo = pk2fp8(wvv[2]*nwv[2]*BSCL, wvv[3]*nwv[3]*BSCL, lo, true);
            unsigned hi = pk2fp8(wvv[4]*nwv[4]*BSCL, wvv[5]*nwv[5]*BSCL, 0u, false);
            hi = pk2fp8(wvv[6]*nwv[6]*BSCL, wvv[7]*nwv[7]*BSCL, hi, true);
            bfr[t][s] = (long)(((unsigned long long)hi << 32) | lo);
            if (t == 0) cp0 += cacc; else cp1 += cacc;
        }
    }
    cp0 += __shfl_xor(cp0, 16); cp0 += __shfl_xor(cp0, 32);
    cp1 += __shfl_xor(cp1, 16); cp1 += __shfl_xor(cp1, 32);

    // ---- prime pipeline: gather batch `bat` into buf0; idx for batch +g ----
    gl_lds16b(xq + (long long)i0 * BROW + sboff, Ash + wave * 1024);
    const int b1 = (bat + g < nbat) ? (bat + g) : bat;
    int inext = knn[min(b1 * ROWS + myrow, nk - 1)];

    int buf = 0;
    for (; bat < nbat; bat += g) {
        // compiler emits s_waitcnt vmcnt(0) lgkmcnt(0) before s_barrier ->
        // buf's DMA writes complete; prior iter's LDS reads drained.
        __syncthreads();

        // ---- issue next batch's gather NOW (in flight during MFMA below) ----
        if (bat + g < nbat) {
            gl_lds16b(xq + (long long)inext * BROW + sboff,
                      Ash + (buf ^ 1) * BUFB + wave * 1024);
            const int b2 = (bat + 2 * g < nbat) ? (bat + 2 * g) : (bat + g);
            inext = knn[min(b2 * ROWS + myrow, nk - 1)];
        }

        // ---- MFMA + maxpool for the 4 queries; paired 64-lane stores ----
        #pragma unroll
        for (int jp = 0; jp < 2; ++jp) {
            float ra0, ra1, rb0, rb1;
            #pragma unroll
            for (int half = 0; half < 2; ++half) {
                const int ql = jp * 2 + half;
                const int r  = ql * 16 + m16;
                long afr[4];
                #pragma unroll
                for (int s = 0; s < 4; ++s) {
                    const int pos = (s * 2 + (qd >> 1)) ^ (r & 7);
                    afr[s] = *(const long*)&Ash[buf * BUFB + r * BROW + pos * 16 + (qd & 1) * 8];
                }
                f32x4 acc0 = {0,0,0,0}, acc1 = {0,0,0,0};
                #pragma unroll
                for (int s = 0; s < 4; ++s) {
                    acc0 = __builtin_amdgcn_mfma_f32_16x16x32_fp8_fp8(
                        afr[s], bfr[0][s], acc0, 0, 0, 0);
                    acc1 = __builtin_amdgcn_mfma_f32_16x16x32_fp8_fp8(
                        afr[s], bfr[1][s], acc1, 0, 0, 0);
                }
                float v0 = fmaxf(fmaxf(acc0[0], acc0[1]), fmaxf(acc0[2], acc0[3]));
                v0 = fmaxf(v0, __shfl_xor(v0, 16));
                v0 = fmaxf(v0, __shfl_xor(v0, 32));
                float v1 = fmaxf(fmaxf(acc1[0], acc1[1]), fmaxf(acc1[2], acc1[3]));
                v1 = fmaxf(v1, __shfl_xor(v1, 16));
                v1 = fmaxf(v1, __shfl_xor(v1, 32));
                if (half == 0) { ra0 = v0; ra1 = v1; }
                else           { rb0 = v0; rb1 = v1; }
            }
            // lanes qd in {0,1}: query jp*2, lanes qd in {2,3}: query jp*2+1
            const float s0 = (qd >> 1) ? rb0 : ra0;
            const float s1 = (qd >> 1) ? rb1 : ra1;
            const float val = ((qd & 1) ? s1 : s0) * IBSCL + ((qd & 1) ? cp1 : cp0);
            const int q = bat * BQ + jp * 2 + (qd >> 1);
            if (q < mq)
                out[q * C_OUT + wave * 32 + (qd & 1) * 16 + m16] = val;
        }
        buf ^= 1;
    }

    // ---- passthrough outputs ----
    const int gtid = blockIdx.x * BLOCK + tid;
    const int gstr = g * BLOCK;
    const int np4 = npcnt >> 2;
    for (int i = gtid; i < np4; i += gstr)
        ((float4*)out_np)[i] = ((const float4*)n_p)[i];
    for (int i = (np4 << 2) + gtid; i < npcnt; i += gstr) out_np[i] = n_p[i];
    if (gtid < 4) out_no[gtid] = (float)n_o[gtid];
}

// ---------------------------------------------------------------------------
// Fallback: single-pass bf16 kernel (R4, proven) for when ws_size is too small.
// ---------------------------------------------------------------------------
__global__ __launch_bounds__(256) void fused_inline_kernel(
    const float* __restrict__ x, const int* __restrict__ knn,
    const float* __restrict__ nw, const float* __restrict__ nb,
    const float* __restrict__ W,
    const float* __restrict__ n_p, const int* __restrict__ n_o,
    float* __restrict__ out, float* __restrict__ out_np, float* __restrict__ out_no,
    int mq, int npcnt)
{
    __shared__ __align__(16) short Ash[2 * 32 * C_IN];

    const int tid  = threadIdx.x;
    const int lane = tid & 63;
    const int wave = tid >> 6;
    const int m16  = lane & 15;
    const int qd   = lane >> 4;

    short8 bfrag[4][4];
    float  cpart[4] = {0.f, 0.f, 0.f, 0.f};
    #pragma unroll
    for (int s = 0; s < 4; ++s) {
        const int k0 = s * 32 + qd * 8;
        const float4 a0 = *(const float4*)(nw + k0);
        const float4 a1 = *(const float4*)(nw + k0 + 4);
        const float4 c0 = *(const float4*)(nb + k0);
        const float4 c1 = *(const float4*)(nb + k0 + 4);
        const float nwv[8] = {a0.x,a0.y,a0.z,a0.w,a1.x,a1.y,a1.z,a1.w};
        const float nbv[8] = {c0.x,c0.y,c0.z,c0.w,c1.x,c1.y,c1.z,c1.w};
        #pragma unroll
        for (int t = 0; t < 4; ++t) {
            const int n = wave * 64 + t * 16 + m16;
            const float4* wp = (const float4*)(W + n * C_IN + k0);
            const float4 w0 = wp[0], w1 = wp[1];
            const float wvv[8] = {w0.x,w0.y,w0.z,w0.w,w1.x,w1.y,w1.z,w1.w};
            short8 b;
            #pragma unroll
            for (int j = 0; j < 8; ++j) {
                b[j] = f2bf_bits(wvv[j] * nwv[j]);
                cpart[t] += nbv[j] * wvv[j];
            }
            bfrag[t][s] = b;
        }
    }
    #pragma unroll
    for (int t = 0; t < 4; ++t) {
        cpart[t] += __shfl_xor(cpart[t], 16);
        cpart[t] += __shfl_xor(cpart[t], 32);
    }
    const float cbias = (qd == 0) ? cpart[0] : (qd == 1) ? cpart[1]
                      : (qd == 2) ? cpart[2] : cpart[3];

    const int sr = tid >> 3;
    const int sc = tid & 7;

    const int nbat = (mq + 1) / 2;
    const int g = gridDim.x;
    const int nk = mq * KNN;

    int bat = blockIdx.x;
    float4 pf[4];
    int idxn;
    {
        const int id0 = knn[min(bat * 32 + sr, nk - 1)];
        const float* xr = x + (long long)id0 * C_IN + sc * 4;
        #pragma unroll
        for (int t = 0; t < 4; ++t) pf[t] = *(const float4*)(xr + t * 32);
        const int b1 = (bat + g < nbat) ? (bat + g) : bat;
        idxn = knn[min(b1 * 32 + sr, nk - 1)];
    }

    int buf = 0;
    for (; bat < nbat; bat += g) {
        float s1 = 0.f, s2 = 0.f;
        #pragma unroll
        for (int t = 0; t < 4; ++t) {
            s1 += pf[t].x + pf[t].y + pf[t].z + pf[t].w;
            s2 += pf[t].x*pf[t].x + pf[t].y*pf[t].y + pf[t].z*pf[t].z + pf[t].w*pf[t].w;
        }
        #pragma unroll
        for (int off = 1; off < 8; off <<= 1) {
            s1 += __shfl_xor(s1, off);
            s2 += __shfl_xor(s2, off);
        }
        const float mu   = s1 * (1.f / 128.f);
        const float rstd = rsqrtf(s2 * (1.f / 128.f) - mu * mu + LN_EPS);
        #pragma unroll
        for (int t = 0; t < 4; ++t) {
            short4_t hb;
            hb[0] = f2bf_bits((pf[t].x - mu) * rstd);
            hb[1] = f2bf_bits((pf[t].y - mu) * rstd);
            hb[2] = f2bf_bits((pf[t].z - mu) * rstd);
            hb[3] = f2bf_bits((pf[t].w - mu) * rstd);
            const int pb = ((sc >> 1) + 4 * t) ^ (sr & 15);
            *(short4_t*)&Ash[buf * 4096 + sr * 128 + pb * 8 + (sc & 1) * 4] = hb;
        }
        __syncthreads();

        if (bat + g < nbat) {
            const float* xr = x + (long long)idxn * C_IN + sc * 4;
            #pragma unroll
            for (int t = 0; t < 4; ++t) pf[t] = *(const float4*)(xr + t * 32);
            const int b2 = (bat + 2 * g < nbat) ? (bat + 2 * g) : (bat + g);
            idxn = knn[min(b2 * 32 + sr, nk - 1)];
        }

        #pragma unroll
        for (int ql = 0; ql < 2; ++ql) {
            short8 afrag[4];
            #pragma unroll
            for (int s = 0; s < 4; ++s) {
                const int pb = (s * 4 + qd) ^ m16;
                afrag[s] = *(const short8*)&Ash[buf * 4096 + (ql * 16 + m16) * 128 + pb * 8];
            }
            f32x4 acc[4] = {{0,0,0,0},{0,0,0,0},{0,0,0,0},{0,0,0,0}};
            #pragma unroll
            for (int s = 0; s < 4; ++s) {
                const bf16x8 av = __builtin_bit_cast(bf16x8, afrag[s]);
                #pragma unroll
                for (int t = 0; t < 4; ++t)
                    acc[t] = __builtin_amdgcn_mfma_f32_16x16x32_bf16(
                        av, __builtin_bit_cast(bf16x8, bfrag[t][s]), acc[t], 0, 0, 0);
            }
            float r[4];
            #pragma unroll
            for (int t = 0; t < 4; ++t) {
                float v = fmaxf(fmaxf(acc[t][0], acc[t][1]), fmaxf(acc[t][2], acc[t][3]));
                v = fmaxf(v, __shfl_xor(v, 16));
                v = fmaxf(v, __shfl_xor(v, 32));
                r[t] = v;
            }
            const float vout = ((qd == 0) ? r[0] : (qd == 1) ? r[1]
                              : (qd == 2) ? r[2] : r[3]) + cbias;
            const int q = bat * 2 + ql;
            if (q < mq) out[q * C_OUT + wave * 64 + lane] = vout;
        }
        buf ^= 1;
    }

    const int gtid = blockIdx.x * 256 + tid;
    const int gstr = g * 256;
    const int np4 = npcnt >> 2;
    for (int i = gtid; i < np4; i += gstr)
        ((float4*)out_np)[i] = ((const float4*)n_p)[i];
    for (int i = (np4 << 2) + gtid; i < npcnt; i += gstr) out_np[i] = n_p[i];
    if (gtid < 4) out_no[gtid] = (float)n_o[gtid];
}

extern "C" void kernel_launch(void* const* d_in, const int* in_sizes, int n_in,
                              void* d_out, int out_size, void* d_ws, size_t ws_size,
                              hipStream_t stream)
{
    const float* x   = (const float*)d_in[1];
    const float* n_p = (const float*)d_in[3];
    const int*   knn = (const int*)  d_in[4];
    const int*   n_o = (const int*)  d_in[5];
    const float* nw  = (const float*)d_in[6];
    const float* nb  = (const float*)d_in[7];
    const float* W   = (const float*)d_in[8];
    float* out = (float*)d_out;

    // in_sizes are ELEMENT counts (mq = in_sizes[4]/16 = 50000 proves it).
    const int n     = in_sizes[1] / C_IN;   // 200000 source rows
    const int mq    = in_sizes[4] / KNN;    // 50000
    const int npcnt = in_sizes[3];          // 150000
    float* out_np = out + (size_t)mq * C_OUT;
    float* out_no = out_np + npcnt;

    const size_t ws_need = (size_t)n * BROW;   // 25.6 MB fp8 table
    if (ws_size >= ws_need) {
        unsigned* xq = (unsigned*)d_ws;
        hipLaunchKernelGGL(lnq_kernel, dim3((n + 7) / 8), dim3(256), 0, stream,
                           x, xq, n);
        hipLaunchKernelGGL(fused_gather_kernel, dim3(NBLK), dim3(BLOCK), 0, stream,
                           (const unsigned char*)xq, knn, nw, nb, W, n_p, n_o,
                           out, out_np, out_no, mq, npcnt);
    } else {
        hipLaunchKernelGGL(fused_inline_kernel, dim3(NBLK), dim3(256), 0, stream,
                           x, knn, nw, nb, W, n_p, n_o, out, out_np, out_no, mq, npcnt);
    }
}